// Round 9
// baseline (6304.498 us; speedup 1.0000x reference)
//
#include <hip/hip_runtime.h>

#define NQ      3136
#define QPAD    3328
#define MM      65536
#define CC      768
#define NQB     13
#define KT2N    24              // K-steps per qb (768/32)
#define TT2     (NQB * KT2N)    // 312

typedef short bf16x8 __attribute__((ext_vector_type(8)));
typedef float f32x16 __attribute__((ext_vector_type(16)));
typedef unsigned short u16x4 __attribute__((ext_vector_type(4)));

#define GLOAD16(gp, lp) __builtin_amdgcn_global_load_lds( \
    (const __attribute__((address_space(1))) void*)(gp), \
    (__attribute__((address_space(3))) void*)(lp), 16, 0, 0)

__device__ __forceinline__ unsigned short f2bf(float f) {
  unsigned u = __float_as_uint(f);
  u += 0x7fffu + ((u >> 16) & 1u);
  return (unsigned short)(u >> 16);
}

// 4-slot swizzle (r5+: measured 0 bank conflicts)
__device__ __forceinline__ int swz4(int s, int row) {
  return s ^ ((row ^ (row >> 2)) & 3);
}

// ---------------- prep: per-row sum of squares ----------------
__global__ __launch_bounds__(256) void prep_sumsq(const float* __restrict__ tok,
                                                  const float* __restrict__ bank,
                                                  float* __restrict__ y2,
                                                  float* __restrict__ x2) {
  int row = blockIdx.x * 4 + (threadIdx.x >> 6);
  int lane = threadIdx.x & 63;
  const float* src;
  float* dst;
  bool zero = false;
  if (row < MM) {
    src = bank + (size_t)row * CC;
    dst = y2 + row;
  } else {
    int rx = row - MM;
    if (rx >= QPAD) return;
    zero = (rx >= NQ);
    src = tok + (size_t)(zero ? 0 : rx) * CC;
    dst = x2 + rx;
  }
  float s = 0.f;
#pragma unroll
  for (int p = 0; p < 3; ++p) {
    float4 v = *reinterpret_cast<const float4*>(src + (lane + p * 64) * 4);
    s += v.x * v.x + v.y * v.y + v.z * v.z + v.w * v.w;
  }
#pragma unroll
  for (int m = 32; m >= 1; m >>= 1) s += __shfl_xor(s, m, 64);
  if (lane == 0) *dst = zero ? 0.f : s;
}

// ---------------- convert to bf16: [tile=(r>>8)*24+kt2][row][4 slots swz4] ------
__global__ __launch_bounds__(256) void convert_bank(const float* __restrict__ bank,
                                                    unsigned short* __restrict__ dst) {
  unsigned idx = blockIdx.x * 256 + threadIdx.x;   // < 65536*96
  unsigned r = idx / 96;
  unsigned g = idx - r * 96;            // global 8-elem slot in row
  unsigned kt2 = g >> 2, s = g & 3;
  const float* src = bank + (size_t)r * CC + g * 8;
  float4 a = *reinterpret_cast<const float4*>(src);
  float4 b = *reinterpret_cast<const float4*>(src + 4);
  u16x4 p0, p1;
  p0[0] = f2bf(a.x); p0[1] = f2bf(a.y); p0[2] = f2bf(a.z); p0[3] = f2bf(a.w);
  p1[0] = f2bf(b.x); p1[1] = f2bf(b.y); p1[2] = f2bf(b.z); p1[3] = f2bf(b.w);
  unsigned tile = (r >> 8) * KT2N + kt2;
  unsigned row = r & 255;
  unsigned short* d = dst + ((size_t)tile << 13) + row * 32 + (swz4(s, row) << 3);
  *reinterpret_cast<u16x4*>(d) = p0;
  *reinterpret_cast<u16x4*>(d + 4) = p1;
}

__global__ __launch_bounds__(256) void convert_tok(const float* __restrict__ tok,
                                                   unsigned short* __restrict__ dst) {
  unsigned idx = blockIdx.x * 256 + threadIdx.x;   // < 3328*96
  unsigned r = idx / 96;
  unsigned g = idx - r * 96;
  unsigned kt2 = g >> 2, s = g & 3;
  unsigned rs = r < NQ ? r : NQ - 1;
  const float* src = tok + (size_t)rs * CC + g * 8;
  float4 a = *reinterpret_cast<const float4*>(src);
  float4 b = *reinterpret_cast<const float4*>(src + 4);
  u16x4 p0, p1;
  p0[0] = f2bf(a.x); p0[1] = f2bf(a.y); p0[2] = f2bf(a.z); p0[3] = f2bf(a.w);
  p1[0] = f2bf(b.x); p1[1] = f2bf(b.y); p1[2] = f2bf(b.z); p1[3] = f2bf(b.w);
  unsigned tile = (r >> 8) * KT2N + kt2;
  unsigned row = r & 255;
  unsigned short* d = dst + ((size_t)tile << 13) + row * 32 + (swz4(s, row) << 3);
  *reinterpret_cast<u16x4*>(d) = p0;
  *reinterpret_cast<u16x4*>(d + 4) = p1;
}

// ---------------- fused distance-GEMM + per-query top-5 ----------------
// 512 blocks = (mtile 0..255) x (qb-half). Half 0: qb 0-6, half 1: qb 7-12.
// 2-slot LDS ring (70KB total) -> 2 blocks/CU: co-resident blocks overlap
// MFMA with LDS/staging phases (m114 wave-level overlap). One barrier/tile.
template <int PRE>
__global__ __launch_bounds__(512, 4) void gemm_topk(
    const float* __restrict__ tok, const float* __restrict__ bank,
    const unsigned short* __restrict__ bswz, const unsigned short* __restrict__ tswz,
    const float* __restrict__ y2g, const float* __restrict__ x2g,
    unsigned* __restrict__ cand) {
  __shared__ __align__(16) char sA[2][16384];    // Y ring (bank rows)
  __shared__ __align__(16) char sB[2][16384];    // X ring (queries)
  __shared__ float y2s[256];
  __shared__ unsigned fscratch[256 * 5];

  int bid = blockIdx.x;
  int b = bid & 255;           // mtile
  int half = bid >> 8;
  int qb0 = half ? 7 : 0;
  int qb1 = half ? NQB : 7;
  int tid = threadIdx.x;
  int lane = tid & 63;
  int wid = tid >> 6;
  int wq = wid & 3;            // 64-query strip
  int wm = wid >> 2;           // 128-row m strip
  int l31 = lane & 31;
  int lhi = lane >> 5;

  // per-thread LDS byte offsets within a 16KB slot
  int offA[4][2], offB[2][2];
#pragma unroll
  for (int mi = 0; mi < 4; ++mi)
#pragma unroll
    for (int ks = 0; ks < 2; ++ks) {
      int row = wm * 128 + mi * 32 + l31;
      offA[mi][ks] = row * 64 + swz4(ks * 2 + lhi, row) * 16;
    }
#pragma unroll
  for (int qj = 0; qj < 2; ++qj)
#pragma unroll
    for (int ks = 0; ks < 2; ++ks) {
      int row = wq * 64 + qj * 32 + l31;
      offB[qj][ks] = row * 64 + swz4(ks * 2 + lhi, row) * 16;
    }

  float thrp[2];
  auto set_thr = [&](int qb) {
#pragma unroll
    for (int qj = 0; qj < 2; ++qj) {
      int qg = qb * 256 + wq * 64 + qj * 32 + l31;
      int qgc = qg < NQ ? qg : NQ - 1;
      float x2q = x2g[qgc];
      thrp[qj] = 768.f - 3.f * sqrtf(1536.f + 4.f * x2q);
    }
  };

  float lv[2][5];
  unsigned li[2][5];
#pragma unroll
  for (int qj = 0; qj < 2; ++qj)
#pragma unroll
    for (int s = 0; s < 5; ++s) { lv[qj][s] = 3.4e38f; li[qj][s] = 0u; }

  f32x16 acc[4][2];
#pragma unroll
  for (int mi = 0; mi < 4; ++mi)
#pragma unroll
    for (int qj = 0; qj < 2; ++qj)
#pragma unroll
      for (int e = 0; e < 16; ++e) acc[mi][qj][e] = 0.f;

  auto insert_pass = [&]() {
#pragma unroll
    for (int mi = 0; mi < 4; ++mi) {
#pragma unroll
      for (int r = 0; r < 16; ++r) {
        int mloc = wm * 128 + mi * 32 + (r & 3) + ((r >> 2) << 3) + (lhi << 2);
        float y2v = y2s[mloc];
#pragma unroll
        for (int qj = 0; qj < 2; ++qj) {
          float d2p = fmaf(-2.f, acc[mi][qj][r], y2v);
          if (d2p < thrp[qj] && d2p < lv[qj][4]) {
            float v = d2p;
            unsigned idv = (unsigned)mloc;
#pragma unroll
            for (int s = 0; s < 5; ++s) {
              bool less = v < lv[qj][s];
              float tv = lv[qj][s]; unsigned ti = li[qj][s];
              if (less) { lv[qj][s] = v; li[qj][s] = idv; v = tv; idv = ti; }
            }
          }
        }
#pragma unroll
        for (int qj = 0; qj < 2; ++qj) acc[mi][qj][r] = 0.f;
      }
    }
  };

  auto flushq = [&](int qb) {
#pragma unroll
    for (int qj = 0; qj < 2; ++qj) {
      float ov[5];
      unsigned oi[5];
#pragma unroll
      for (int j = 0; j < 5; ++j) {
        ov[j] = __shfl_xor(lv[qj][j], 32, 64);
        oi[j] = (unsigned)__shfl_xor((int)li[qj][j], 32, 64);
      }
#pragma unroll
      for (int j = 0; j < 5; ++j) {
        float v = ov[j];
        unsigned idv = oi[j];
#pragma unroll
        for (int s = 0; s < 5; ++s) {
          bool less = v < lv[qj][s];
          float tv = lv[qj][s]; unsigned ti = li[qj][s];
          if (less) { lv[qj][s] = v; li[qj][s] = idv; v = tv; idv = ti; }
        }
      }
    }
    unsigned pk[2][5];
#pragma unroll
    for (int qj = 0; qj < 2; ++qj)
#pragma unroll
      for (int s = 0; s < 5; ++s)
        pk[qj][s] = (lv[qj][s] >= 3.0e38f) ? 0xFFFFFFFFu
                    : ((__float_as_uint(fmaxf(lv[qj][s], 0.f)) & 0xFFFFFF00u) | li[qj][s]);
    if (wm == 1 && lhi == 0) {
#pragma unroll
      for (int qj = 0; qj < 2; ++qj) {
        int ql = wq * 64 + qj * 32 + l31;
#pragma unroll
        for (int s = 0; s < 5; ++s) fscratch[ql * 5 + s] = pk[qj][s];
      }
    }
    __syncthreads();
    if (wm == 0 && lhi == 0) {
#pragma unroll
      for (int qj = 0; qj < 2; ++qj) {
        int ql = wq * 64 + qj * 32 + l31;
#pragma unroll
        for (int j = 0; j < 5; ++j) {
          unsigned v = fscratch[ql * 5 + j];
#pragma unroll
          for (int s = 0; s < 5; ++s) {
            unsigned tv = pk[qj][s];
            bool less = v < tv;
            if (less) { pk[qj][s] = v; v = tv; }
          }
        }
        size_t qg = (size_t)(qb * 256 + ql);
        unsigned* cp = cand + (qg * 256 + b) * 5;
#pragma unroll
        for (int s = 0; s < 5; ++s) cp[s] = pk[qj][s];
      }
    }
#pragma unroll
    for (int qj = 0; qj < 2; ++qj)
#pragma unroll
      for (int s = 0; s < 5; ++s) { lv[qj][s] = 3.4e38f; li[qj][s] = 0u; }
  };

  if (tid < 256) y2s[tid] = y2g[b * 256 + tid];
  set_thr(qb0);

  if constexpr (PRE) {
    auto stageT = [&](int qb, int kt, int slot) {
      const char* gA = (const char*)bswz + ((size_t)(b * KT2N + kt) << 14);
      GLOAD16(gA + (tid << 4), &sA[slot][tid << 4]);
      GLOAD16(gA + 8192 + (tid << 4), &sA[slot][8192 + (tid << 4)]);
      const char* gB = (const char*)tswz + ((size_t)(qb * KT2N + kt) << 14);
      GLOAD16(gB + (tid << 4), &sB[slot][tid << 4]);
      GLOAD16(gB + 8192 + (tid << 4), &sB[slot][8192 + (tid << 4)]);
    };
    int nql = qb1 - qb0;
    int TL = nql * KT2N;
    stageT(qb0, 0, 0);
    asm volatile("s_waitcnt vmcnt(0)" ::: "memory");
    __builtin_amdgcn_sched_barrier(0);
    __builtin_amdgcn_s_barrier();

    for (int ql = 0; ql < nql; ++ql) {
      int qb = qb0 + ql;
      for (int g = 0; g < KT2N / 2; ++g) {
#pragma unroll
        for (int u = 0; u < 2; ++u) {
          int t = ql * KT2N + g * 2 + u;     // slot == t & 1 == u
          int tn = t + 1 < TL ? t + 1 : TL - 1;
          stageT(qb0 + tn / KT2N, tn % KT2N, u ^ 1);
          // ds_read fragments of tile t from slot u
          bf16x8 af[4][2], bf[2][2];
#pragma unroll
          for (int qj = 0; qj < 2; ++qj)
#pragma unroll
            for (int ks = 0; ks < 2; ++ks)
              bf[qj][ks] = *reinterpret_cast<const bf16x8*>(&sB[u][offB[qj][ks]]);
#pragma unroll
          for (int mi = 0; mi < 4; ++mi)
#pragma unroll
            for (int ks = 0; ks < 2; ++ks)
              af[mi][ks] = *reinterpret_cast<const bf16x8*>(&sA[u][offA[mi][ks]]);
          // 16-MFMA cluster (compiler inserts fine-grained lgkmcnt)
          __builtin_amdgcn_s_setprio(1);
#pragma unroll
          for (int ks = 0; ks < 2; ++ks)
#pragma unroll
            for (int mi = 0; mi < 4; ++mi) {
              acc[mi][0] = __builtin_amdgcn_mfma_f32_32x32x16_bf16(af[mi][ks], bf[0][ks], acc[mi][0], 0, 0, 0);
              acc[mi][1] = __builtin_amdgcn_mfma_f32_32x32x16_bf16(af[mi][ks], bf[1][ks], acc[mi][1], 0, 0, 0);
            }
          __builtin_amdgcn_s_setprio(0);
          // drain next-tile stage; co-resident block hides the residual
          asm volatile("s_waitcnt vmcnt(0)" ::: "memory");
          __builtin_amdgcn_sched_barrier(0);
          __builtin_amdgcn_s_barrier();
        }
      }
      insert_pass();
      flushq(qb);
      if (qb + 1 < qb1) set_thr(qb + 1);
    }
  } else {
    // fallback: stage fp32->bf16 by VALU each step, plain 2-barrier loop
    for (int qbc = qb0; qbc < qb1; ++qbc) {
      for (int kt2c = 0; kt2c < KT2N; ++kt2c) {
        __syncthreads();
#pragma unroll
        for (int j = 0; j < 2; ++j) {
          int u = tid * 2 + j;
          int row = u >> 2, s = u & 3;
          const float* srcA = bank + (size_t)(b * 256 + row) * CC + kt2c * 32 + s * 8;
          float4 a = *reinterpret_cast<const float4*>(srcA);
          float4 b4 = *reinterpret_cast<const float4*>(srcA + 4);
          u16x4 p0, p1;
          p0[0] = f2bf(a.x); p0[1] = f2bf(a.y); p0[2] = f2bf(a.z); p0[3] = f2bf(a.w);
          p1[0] = f2bf(b4.x); p1[1] = f2bf(b4.y); p1[2] = f2bf(b4.z); p1[3] = f2bf(b4.w);
          char* d = &sA[0][row * 64 + swz4(s, row) * 16];
          *reinterpret_cast<u16x4*>(d) = p0;
          *reinterpret_cast<u16x4*>(d + 8) = p1;
          int srow = qbc * 256 + row;
          srow = srow < NQ ? srow : NQ - 1;
          const float* srcB = tok + (size_t)srow * CC + kt2c * 32 + s * 8;
          a = *reinterpret_cast<const float4*>(srcB);
          b4 = *reinterpret_cast<const float4*>(srcB + 4);
          p0[0] = f2bf(a.x); p0[1] = f2bf(a.y); p0[2] = f2bf(a.z); p0[3] = f2bf(a.w);
          p1[0] = f2bf(b4.x); p1[1] = f2bf(b4.y); p1[2] = f2bf(b4.z); p1[3] = f2bf(b4.w);
          d = &sB[0][row * 64 + swz4(s, row) * 16];
          *reinterpret_cast<u16x4*>(d) = p0;
          *reinterpret_cast<u16x4*>(d + 8) = p1;
        }
        __syncthreads();
        bf16x8 af[4][2], bf[2][2];
#pragma unroll
        for (int qj = 0; qj < 2; ++qj)
#pragma unroll
          for (int ks = 0; ks < 2; ++ks)
            bf[qj][ks] = *reinterpret_cast<const bf16x8*>(&sB[0][offB[qj][ks]]);
#pragma unroll
        for (int mi = 0; mi < 4; ++mi)
#pragma unroll
          for (int ks = 0; ks < 2; ++ks)
            af[mi][ks] = *reinterpret_cast<const bf16x8*>(&sA[0][offA[mi][ks]]);
#pragma unroll
        for (int ks = 0; ks < 2; ++ks)
#pragma unroll
          for (int mi = 0; mi < 4; ++mi) {
            acc[mi][0] = __builtin_amdgcn_mfma_f32_32x32x16_bf16(af[mi][ks], bf[0][ks], acc[mi][0], 0, 0, 0);
            acc[mi][1] = __builtin_amdgcn_mfma_f32_32x32x16_bf16(af[mi][ks], bf[1][ks], acc[mi][1], 0, 0, 0);
          }
      }
      __syncthreads();
      insert_pass();
      flushq(qbc);
      if (qbc + 1 < qb1) set_thr(qbc + 1);
    }
  }
}

// ---------------- merge candidates, exact fp32 rescoring, final score ----------------
__global__ __launch_bounds__(256) void merge_rescore(
    const float* __restrict__ tok, const float* __restrict__ bank,
    const unsigned* __restrict__ cand, float* __restrict__ out) {
  int q = blockIdx.x * 4 + (threadIdx.x >> 6);
  int lane = threadIdx.x & 63;
  const unsigned* cp = cand + (size_t)q * 1280;
  unsigned e[20];   // 4 blocks x 5 entries per lane
#pragma unroll
  for (int j = 0; j < 20; ++j) e[j] = cp[lane * 20 + j];
  unsigned gids[8];
#pragma unroll
  for (int r = 0; r < 8; ++r) {
    unsigned bv = e[0];
#pragma unroll
    for (int j = 1; j < 20; ++j) bv = e[j] < bv ? e[j] : bv;
    unsigned rv = bv;
    int rl = lane;
#pragma unroll
    for (int m = 32; m >= 1; m >>= 1) {
      unsigned ov = (unsigned)__shfl_xor((int)rv, m, 64);
      int ol = __shfl_xor(rl, m, 64);
      if (ov < rv || (ov == rv && ol < rl)) { rv = ov; rl = ol; }
    }
    unsigned gid = 0;
    if (lane == rl) {
      bool done = false;
#pragma unroll
      for (int j = 0; j < 20; ++j) {
        if (!done && e[j] == rv) {
          gid = (unsigned)((lane * 4 + j / 5) * 256) + (e[j] & 255u);
          e[j] = 0xFFFFFFFFu;
          done = true;
        }
      }
    }
    gids[r] = (unsigned)__shfl((int)gid, rl, 64);
  }
  float xv[12];
  {
    const float* xp = tok + (size_t)q * CC + lane * 12;
    float4 a = *reinterpret_cast<const float4*>(xp);
    float4 bq = *reinterpret_cast<const float4*>(xp + 4);
    float4 cc4 = *reinterpret_cast<const float4*>(xp + 8);
    xv[0] = a.x; xv[1] = a.y; xv[2] = a.z; xv[3] = a.w;
    xv[4] = bq.x; xv[5] = bq.y; xv[6] = bq.z; xv[7] = bq.w;
    xv[8] = cc4.x; xv[9] = cc4.y; xv[10] = cc4.z; xv[11] = cc4.w;
  }
  float d2e[8];
#pragma unroll
  for (int r = 0; r < 8; ++r) {
    const float* yp = bank + (size_t)(gids[r] & (MM - 1)) * CC + lane * 12;
    float4 a = *reinterpret_cast<const float4*>(yp);
    float4 bq = *reinterpret_cast<const float4*>(yp + 4);
    float4 cc4 = *reinterpret_cast<const float4*>(yp + 8);
    float yv[12];
    yv[0] = a.x; yv[1] = a.y; yv[2] = a.z; yv[3] = a.w;
    yv[4] = bq.x; yv[5] = bq.y; yv[6] = bq.z; yv[7] = bq.w;
    yv[8] = cc4.x; yv[9] = cc4.y; yv[10] = cc4.z; yv[11] = cc4.w;
    float s = 0.f;
#pragma unroll
    for (int e2 = 0; e2 < 12; ++e2) {
      float d = xv[e2] - yv[e2];
      s = fmaf(d, d, s);
    }
#pragma unroll
    for (int m = 32; m >= 1; m >>= 1) s += __shfl_xor(s, m, 64);
    d2e[r] = s;
  }
  float d1sq = 0.f, d5sq = 0.f;
#pragma unroll
  for (int r5 = 0; r5 < 5; ++r5) {
    float bv = d2e[0];
    int bj = 0;
#pragma unroll
    for (int j = 1; j < 8; ++j)
      if (d2e[j] < bv) { bv = d2e[j]; bj = j; }
    if (r5 == 0) d1sq = bv;
    if (r5 == 4) d5sq = bv;
#pragma unroll
    for (int j = 0; j < 8; ++j)
      if (j == bj) d2e[j] = 3.4e38f;
  }
  float d1 = sqrtf(fmaxf(d1sq, 0.f));
  float d5 = sqrtf(fmaxf(d5sq, 0.f));
  float gap = fmaxf(d5 - d1, 0.f);
  float sc = d1 * (1.f - expf(-gap));
  if (lane == 0) out[q] = sc;
}

extern "C" void kernel_launch(void* const* d_in, const int* in_sizes, int n_in,
                              void* d_out, int out_size, void* d_ws, size_t ws_size,
                              hipStream_t stream) {
  const float* tok = (const float*)d_in[0];   // 3136x768 fp32
  const float* bank = (const float*)d_in[1];  // 65536x768 fp32
  float* out = (float*)d_out;                 // 3136 fp32
  char* ws = (char*)d_ws;
  float* y2 = (float*)ws;                                   // 256KB
  float* x2 = (float*)(ws + 262144);                        // 13KB
  unsigned* cand = (unsigned*)(ws + 1048576);               // 3328*256*5*4 = 17.04MB
  unsigned short* bswz = (unsigned short*)(ws + 18874368);  // 100.66MB
  unsigned short* tswz = (unsigned short*)(ws + 119537664); // 4.87MB
  const size_t WS_NEED = 124649472ull;

  prep_sumsq<<<(MM + QPAD) / 4, 256, 0, stream>>>(tok, bank, y2, x2);
  if (ws_size >= WS_NEED) {
    convert_bank<<<(MM * 96) / 256, 256, 0, stream>>>(bank, bswz);
    convert_tok<<<(QPAD * 96) / 256, 256, 0, stream>>>(tok, tswz);
    gemm_topk<1><<<512, 512, 0, stream>>>(tok, bank, bswz, tswz, y2, x2, cand);
  } else {
    gemm_topk<0><<<512, 512, 0, stream>>>(tok, bank, bswz, tswz, y2, x2, cand);
  }
  merge_rescore<<<NQ / 4, 256, 0, stream>>>(tok, bank, cand, out);
}

// Round 10
// 628.921 us; speedup vs baseline: 10.0243x; 10.0243x over previous
//
#include <hip/hip_runtime.h>

#define NQ      3136
#define QPAD    3328
#define MM      65536
#define CC      768
#define NQB     13
#define KTILES  12
#define TT      (NQB * KTILES)   // 156 BK64 tiles
#define NITER   (TT / 2)         // 78

typedef short bf16x8 __attribute__((ext_vector_type(8)));
typedef float f32x4  __attribute__((ext_vector_type(4)));
typedef unsigned short u16x4 __attribute__((ext_vector_type(4)));

#define GLOAD16(gp, lp) __builtin_amdgcn_global_load_lds( \
    (const __attribute__((address_space(1))) void*)(gp), \
    (__attribute__((address_space(3))) void*)(lp), 16, 0, 0)

#define BARR __builtin_amdgcn_s_barrier()
#define VMW8  asm volatile("s_waitcnt vmcnt(8)" ::: "memory")
#define VMW10 asm volatile("s_waitcnt vmcnt(10)" ::: "memory")

__device__ __forceinline__ unsigned short f2bf(float f) {
  unsigned u = __float_as_uint(f);
  u += 0x7fffu + ((u >> 16) & 1u);
  return (unsigned short)(u >> 16);
}

// slot swizzle (r5/r6: measured 0 bank conflicts)
__device__ __forceinline__ int swz(int s, int row) {
  return s ^ (row & 7) ^ ((row >> 3) & 7);
}

// ---------------- prep: per-row sum of squares ----------------
__global__ __launch_bounds__(256) void prep_sumsq(const float* __restrict__ tok,
                                                  const float* __restrict__ bank,
                                                  float* __restrict__ y2,
                                                  float* __restrict__ x2) {
  int row = blockIdx.x * 4 + (threadIdx.x >> 6);
  int lane = threadIdx.x & 63;
  const float* src;
  float* dst;
  bool zero = false;
  if (row < MM) {
    src = bank + (size_t)row * CC;
    dst = y2 + row;
  } else {
    int rx = row - MM;
    if (rx >= QPAD) return;
    zero = (rx >= NQ);
    src = tok + (size_t)(zero ? 0 : rx) * CC;
    dst = x2 + rx;
  }
  float s = 0.f;
#pragma unroll
  for (int p = 0; p < 3; ++p) {
    float4 v = *reinterpret_cast<const float4*>(src + (lane + p * 64) * 4);
    s += v.x * v.x + v.y * v.y + v.z * v.z + v.w * v.w;
  }
#pragma unroll
  for (int m = 32; m >= 1; m >>= 1) s += __shfl_xor(s, m, 64);
  if (lane == 0) *dst = zero ? 0.f : s;
}

// ---------------- convert to bf16: 32KB tiles [tile][row 256][8 slots swz] ----
__global__ __launch_bounds__(256) void convert_bank(const float* __restrict__ bank,
                                                    unsigned short* __restrict__ dst) {
  unsigned idx = blockIdx.x * 256 + threadIdx.x;   // < 65536*96
  unsigned r = idx / 96;
  unsigned cc = idx - r * 96;
  unsigned kt = cc >> 3, s = cc & 7;
  const float* src = bank + (size_t)r * CC + kt * 64 + s * 8;
  float4 a = *reinterpret_cast<const float4*>(src);
  float4 b = *reinterpret_cast<const float4*>(src + 4);
  u16x4 p0, p1;
  p0[0] = f2bf(a.x); p0[1] = f2bf(a.y); p0[2] = f2bf(a.z); p0[3] = f2bf(a.w);
  p1[0] = f2bf(b.x); p1[1] = f2bf(b.y); p1[2] = f2bf(b.z); p1[3] = f2bf(b.w);
  unsigned tile = (r >> 8) * 12 + kt;
  unsigned row = r & 255;
  unsigned short* d = dst + ((size_t)tile << 14) + row * 64 + (swz(s, row) << 3);
  *reinterpret_cast<u16x4*>(d) = p0;
  *reinterpret_cast<u16x4*>(d + 4) = p1;
}

__global__ __launch_bounds__(256) void convert_tok(const float* __restrict__ tok,
                                                   unsigned short* __restrict__ dst) {
  unsigned idx = blockIdx.x * 256 + threadIdx.x;   // < 3328*96
  unsigned r = idx / 96;
  unsigned cc = idx - r * 96;
  unsigned kt = cc >> 3, s = cc & 7;
  unsigned rs = r < NQ ? r : NQ - 1;
  const float* src = tok + (size_t)rs * CC + kt * 64 + s * 8;
  float4 a = *reinterpret_cast<const float4*>(src);
  float4 b = *reinterpret_cast<const float4*>(src + 4);
  u16x4 p0, p1;
  p0[0] = f2bf(a.x); p0[1] = f2bf(a.y); p0[2] = f2bf(a.z); p0[3] = f2bf(a.w);
  p1[0] = f2bf(b.x); p1[1] = f2bf(b.y); p1[2] = f2bf(b.z); p1[3] = f2bf(b.w);
  unsigned tile = (r >> 8) * 12 + kt;
  unsigned row = r & 255;
  unsigned short* d = dst + ((size_t)tile << 14) + row * 64 + (swz(s, row) << 3);
  *reinterpret_cast<u16x4*>(d) = p0;
  *reinterpret_cast<u16x4*>(d + 4) = p1;
}

// ---------------- fused distance-GEMM + per-query top-5 (m201 8-phase port) ----
// 256 blocks, block b = mtile (256 bank rows). 13 qb x 12 BK64-tiles = 156 tiles,
// processed 2/iter. LDS [A0|B0|A1|B1] 4x32KB double buffer. 8 phases/iter:
// {frag ds_reads | half-tile stage -> s_barrier -> setprio+16 MFMA -> vmcnt -> s_barrier}.
// Stages target tiles t+2/t+3; each LDS half staged only after its last reader
// phase's barrier; vmcnt(8)@ph2/4/6, vmcnt(10)@ph8 (derived FIFO counts).
template <int PRE>
__global__ __launch_bounds__(512, 2) void gemm_topk(
    const float* __restrict__ tok, const float* __restrict__ bank,
    const unsigned short* __restrict__ bswz, const unsigned short* __restrict__ tswz,
    const float* __restrict__ y2g, const float* __restrict__ x2g,
    unsigned* __restrict__ cand) {
  __shared__ __align__(16) char lds[131072];     // [A0 32K][B0 32K][A1 32K][B1 32K]
  __shared__ float y2s[256];
  __shared__ unsigned fscratch[256 * 5];

  int b = blockIdx.x;          // mtile
  int tid = threadIdx.x;
  int lane = tid & 63;
  int wid = tid >> 6;
  int wq = wid & 3;            // 64-query strip
  int wm = wid >> 2;           // 128-row m strip
  int l15 = lane & 15;
  int g4 = lane >> 4;

  const char* aBase = (const char*)bswz + ((size_t)b * 12 << 15);

  f32x4 acc[8][4];
#pragma unroll
  for (int mi = 0; mi < 8; ++mi)
#pragma unroll
    for (int qj = 0; qj < 4; ++qj) {
      f32x4 z = {0.f, 0.f, 0.f, 0.f};
      acc[mi][qj] = z;
    }
  bf16x8 aF[4][2];   // current A-half fragments
  bf16x8 bF[4][2];   // all B fragments of current tile

  auto readA = [&](int half, int dbuf) {
    const char* base = lds + dbuf * 65536;
#pragma unroll
    for (int i = 0; i < 4; ++i) {
      int row = wm * 128 + (half * 4 + i) * 16 + l15;
#pragma unroll
      for (int kk = 0; kk < 2; ++kk)
        aF[i][kk] = *reinterpret_cast<const bf16x8*>(
            base + row * 128 + (swz(kk * 4 + g4, row) << 4));
    }
  };
  auto readB = [&](int qh, int dbuf) {
    const char* base = lds + dbuf * 65536 + 32768;
#pragma unroll
    for (int j = 0; j < 2; ++j) {
      int row = wq * 64 + (qh * 2 + j) * 16 + l15;
#pragma unroll
      for (int kk = 0; kk < 2; ++kk)
        bF[qh * 2 + j][kk] = *reinterpret_cast<const bf16x8*>(
            base + row * 128 + (swz(kk * 4 + g4, row) << 4));
    }
  };
  auto MMA = [&](int mh, int qh) {
    __builtin_amdgcn_s_setprio(1);
#pragma unroll
    for (int kk = 0; kk < 2; ++kk)
#pragma unroll
      for (int i = 0; i < 4; ++i)
#pragma unroll
        for (int j = 0; j < 2; ++j)
          acc[mh * 4 + i][qh * 2 + j] = __builtin_amdgcn_mfma_f32_16x16x32_bf16(
              aF[i][kk], bF[qh * 2 + j][kk], acc[mh * 4 + i][qh * 2 + j], 0, 0, 0);
    __builtin_amdgcn_s_setprio(0);
  };
  auto stA = [&](int kt, int h, int dbuf) {
    const char* src = aBase + ((size_t)kt << 15) + h * 16384 + (tid << 4);
    char* dst = lds + dbuf * 65536 + h * 16384 + (tid << 4);
    GLOAD16(src, dst);
    GLOAD16(src + 8192, dst + 8192);
  };
  auto stB = [&](int T, int h, int dbuf) {
    const char* src = (const char*)tswz + ((size_t)T << 15) + h * 16384 + (tid << 4);
    char* dst = lds + dbuf * 65536 + 32768 + h * 16384 + (tid << 4);
    GLOAD16(src, dst);
    GLOAD16(src + 8192, dst + 8192);
  };

  auto insertflush = [&](int qb) {
#pragma unroll
    for (int qj = 0; qj < 4; ++qj) {
      int ql = wq * 64 + qj * 16 + l15;
      int qg = qb * 256 + ql;
      float x2q = x2g[qg < NQ ? qg : NQ - 1];
      float thr = 768.f - 3.f * sqrtf(1536.f + 4.f * x2q);
      float lv[5];
      unsigned li5[5];
#pragma unroll
      for (int s = 0; s < 5; ++s) { lv[s] = 3.4e38f; li5[s] = 0u; }
#pragma unroll
      for (int mi = 0; mi < 8; ++mi)
#pragma unroll
        for (int r = 0; r < 4; ++r) {
          int mloc = wm * 128 + mi * 16 + g4 * 4 + r;
          float d2p = fmaf(-2.f, acc[mi][qj][r], y2s[mloc]);
          if (d2p < thr && d2p < lv[4]) {
            float v = d2p;
            unsigned idv = (unsigned)mloc;
#pragma unroll
            for (int s = 0; s < 5; ++s) {
              bool less = v < lv[s];
              float tv = lv[s]; unsigned ti = li5[s];
              if (less) { lv[s] = v; li5[s] = idv; v = tv; idv = ti; }
            }
          }
          acc[mi][qj][r] = 0.f;
        }
      // union across the 4 lanes (g4 groups) holding this q column
#pragma unroll
      for (int md = 16; md <= 32; md <<= 1) {
        float ov[5];
        unsigned oi[5];
#pragma unroll
        for (int j = 0; j < 5; ++j) {
          ov[j] = __shfl_xor(lv[j], md, 64);
          oi[j] = (unsigned)__shfl_xor((int)li5[j], md, 64);
        }
#pragma unroll
        for (int j = 0; j < 5; ++j) {
          float v = ov[j];
          unsigned idv = oi[j];
#pragma unroll
          for (int s = 0; s < 5; ++s) {
            bool less = v < lv[s];
            float tv = lv[s]; unsigned ti = li5[s];
            if (less) { lv[s] = v; li5[s] = idv; v = tv; idv = ti; }
          }
        }
      }
      unsigned pk[5];
#pragma unroll
      for (int s = 0; s < 5; ++s)
        pk[s] = (lv[s] >= 3.0e38f) ? 0xFFFFFFFFu
                : ((__float_as_uint(fmaxf(lv[s], 0.f)) & 0xFFFFFF00u) | li5[s]);
      if (wm == 1 && lane < 16) {
#pragma unroll
        for (int s = 0; s < 5; ++s) fscratch[ql * 5 + s] = pk[s];
      }
      __syncthreads();
      if (wm == 0 && lane < 16) {
#pragma unroll
        for (int j = 0; j < 5; ++j) {
          unsigned v = fscratch[ql * 5 + j];
#pragma unroll
          for (int s = 0; s < 5; ++s) {
            unsigned tv = pk[s];
            if (v < tv) { pk[s] = v; v = tv; }
          }
        }
        unsigned* cp = cand + ((size_t)qg * 256 + b) * 5;
#pragma unroll
        for (int s = 0; s < 5; ++s) cp[s] = pk[s];
      }
      __syncthreads();
    }
  };

  if (tid < 256) y2s[tid] = y2g[b * 256 + tid];

  if constexpr (PRE) {
    // prologue: stage tiles 0 (dbuf0) and 1 (dbuf1), order B.h0,B.h1,A.h0,A.h1
    stB(0, 0, 0); stB(0, 1, 0); stA(0, 0, 0); stA(0, 1, 0);
    stB(1, 0, 1); stB(1, 1, 1); stA(1, 0, 1); stA(1, 1, 1);
    VMW10;               // tile0 B.h0,B.h1,A.h0 resident
    BARR;

    for (int it = 0; it < NITER; ++it) {
      int TC = 2 * it + 2; if (TC > TT - 1) TC = TT - 1;
      int TD = 2 * it + 3; if (TD > TT - 1) TD = TT - 1;
      int ktC = TC % 12, ktD = TD % 12;
      // ---- tile 2*it in dbuf0 ----
      // ph1
      readB(0, 0); readA(0, 0);
      BARR;
      MMA(0, 0);
      BARR;
      // ph2
      readB(1, 0);
      BARR;
      MMA(0, 1);
      VMW8;              // ensures A(t).h1 resident (staged 2 iters ago)
      BARR;
      // ph3
      readA(1, 0);
      stB(TC, 0, 0);     // B(t) fully read (ph1-2) -> safe to overwrite
      BARR;
      MMA(1, 1);
      BARR;
      // ph4
      stB(TC, 1, 0); stA(ktC, 0, 0);   // A(t) fully read (ph1,ph3)
      BARR;
      MMA(1, 0);
      VMW8;              // ensures B(t+1).h0/h1, A(t+1).h0 resident
      BARR;
      // ---- tile 2*it+1 in dbuf1 ----
      // ph5
      stA(ktC, 1, 0);
      readB(0, 1); readA(0, 1);
      BARR;
      MMA(0, 0);
      BARR;
      // ph6
      readB(1, 1);
      BARR;
      MMA(0, 1);
      VMW8;              // ensures A(t+1).h1 resident
      BARR;
      // ph7
      readA(1, 1);
      stB(TD, 0, 1); stB(TD, 1, 1);
      BARR;
      MMA(1, 1);
      BARR;
      // ph8
      stA(ktD, 0, 1); stA(ktD, 1, 1);
      BARR;
      MMA(1, 0);
      VMW10;             // ensures B(t+2).h0/h1, A(t+2).h0 resident for next ph1
      BARR;
      if ((it % 6) == 5) insertflush(it / 6);
    }
  } else {
    // fallback: single-buffer BK64, stage fp32->bf16 by VALU
    for (int T = 0; T < TT; ++T) {
      int qb = T / 12, kt = T % 12;
      __syncthreads();
#pragma unroll
      for (int i = 0; i < 4; ++i) {
        int u = tid + i * 512;
        int row = u >> 3, s = u & 7;
        const float* sa = bank + (size_t)(b * 256 + row) * CC + kt * 64 + s * 8;
        float4 a = *reinterpret_cast<const float4*>(sa);
        float4 c = *reinterpret_cast<const float4*>(sa + 4);
        u16x4 p0, p1;
        p0[0] = f2bf(a.x); p0[1] = f2bf(a.y); p0[2] = f2bf(a.z); p0[3] = f2bf(a.w);
        p1[0] = f2bf(c.x); p1[1] = f2bf(c.y); p1[2] = f2bf(c.z); p1[3] = f2bf(c.w);
        char* d = lds + row * 128 + (swz(s, row) << 4);
        *reinterpret_cast<u16x4*>(d) = p0;
        *reinterpret_cast<u16x4*>(d + 8) = p1;
        int qr = qb * 256 + row;
        qr = qr < NQ ? qr : NQ - 1;
        const float* sb = tok + (size_t)qr * CC + kt * 64 + s * 8;
        a = *reinterpret_cast<const float4*>(sb);
        c = *reinterpret_cast<const float4*>(sb + 4);
        p0[0] = f2bf(a.x); p0[1] = f2bf(a.y); p0[2] = f2bf(a.z); p0[3] = f2bf(a.w);
        p1[0] = f2bf(c.x); p1[1] = f2bf(c.y); p1[2] = f2bf(c.z); p1[3] = f2bf(c.w);
        d = lds + 32768 + row * 128 + (swz(s, row) << 4);
        *reinterpret_cast<u16x4*>(d) = p0;
        *reinterpret_cast<u16x4*>(d + 8) = p1;
      }
      __syncthreads();
      readB(0, 0); readB(1, 0);
      readA(0, 0); MMA(0, 0); MMA(0, 1);
      readA(1, 0); MMA(1, 0); MMA(1, 1);
      if (kt == 11) {
        __syncthreads();
        insertflush(qb);
      }
    }
  }
}

// ---------------- merge candidates, exact fp32 rescoring, final score ----------------
__global__ __launch_bounds__(256) void merge_rescore(
    const float* __restrict__ tok, const float* __restrict__ bank,
    const unsigned* __restrict__ cand, float* __restrict__ out) {
  int q = blockIdx.x * 4 + (threadIdx.x >> 6);
  int lane = threadIdx.x & 63;
  const unsigned* cp = cand + (size_t)q * 1280;
  unsigned e[20];   // 4 blocks x 5 entries per lane
#pragma unroll
  for (int j = 0; j < 20; ++j) e[j] = cp[lane * 20 + j];
  unsigned gids[8];
#pragma unroll
  for (int r = 0; r < 8; ++r) {
    unsigned bv = e[0];
#pragma unroll
    for (int j = 1; j < 20; ++j) bv = e[j] < bv ? e[j] : bv;
    unsigned rv = bv;
    int rl = lane;
#pragma unroll
    for (int m = 32; m >= 1; m >>= 1) {
      unsigned ov = (unsigned)__shfl_xor((int)rv, m, 64);
      int ol = __shfl_xor(rl, m, 64);
      if (ov < rv || (ov == rv && ol < rl)) { rv = ov; rl = ol; }
    }
    unsigned gid = 0;
    if (lane == rl) {
      bool done = false;
#pragma unroll
      for (int j = 0; j < 20; ++j) {
        if (!done && e[j] == rv) {
          gid = (unsigned)((lane * 4 + j / 5) * 256) + (e[j] & 255u);
          e[j] = 0xFFFFFFFFu;
          done = true;
        }
      }
    }
    gids[r] = (unsigned)__shfl((int)gid, rl, 64);
  }
  float xv[12];
  {
    const float* xp = tok + (size_t)q * CC + lane * 12;
    float4 a = *reinterpret_cast<const float4*>(xp);
    float4 bq = *reinterpret_cast<const float4*>(xp + 4);
    float4 cc4 = *reinterpret_cast<const float4*>(xp + 8);
    xv[0] = a.x; xv[1] = a.y; xv[2] = a.z; xv[3] = a.w;
    xv[4] = bq.x; xv[5] = bq.y; xv[6] = bq.z; xv[7] = bq.w;
    xv[8] = cc4.x; xv[9] = cc4.y; xv[10] = cc4.z; xv[11] = cc4.w;
  }
  float d2e[8];
#pragma unroll
  for (int r = 0; r < 8; ++r) {
    const float* yp = bank + (size_t)(gids[r] & (MM - 1)) * CC + lane * 12;
    float4 a = *reinterpret_cast<const float4*>(yp);
    float4 bq = *reinterpret_cast<const float4*>(yp + 4);
    float4 cc4 = *reinterpret_cast<const float4*>(yp + 8);
    float yv[12];
    yv[0] = a.x; yv[1] = a.y; yv[2] = a.z; yv[3] = a.w;
    yv[4] = bq.x; yv[5] = bq.y; yv[6] = bq.z; yv[7] = bq.w;
    yv[8] = cc4.x; yv[9] = cc4.y; yv[10] = cc4.z; yv[11] = cc4.w;
    float s = 0.f;
#pragma unroll
    for (int e2 = 0; e2 < 12; ++e2) {
      float d = xv[e2] - yv[e2];
      s = fmaf(d, d, s);
    }
#pragma unroll
    for (int m = 32; m >= 1; m >>= 1) s += __shfl_xor(s, m, 64);
    d2e[r] = s;
  }
  float d1sq = 0.f, d5sq = 0.f;
#pragma unroll
  for (int r5 = 0; r5 < 5; ++r5) {
    float bv = d2e[0];
    int bj = 0;
#pragma unroll
    for (int j = 1; j < 8; ++j)
      if (d2e[j] < bv) { bv = d2e[j]; bj = j; }
    if (r5 == 0) d1sq = bv;
    if (r5 == 4) d5sq = bv;
#pragma unroll
    for (int j = 0; j < 8; ++j)
      if (j == bj) d2e[j] = 3.4e38f;
  }
  float d1 = sqrtf(fmaxf(d1sq, 0.f));
  float d5 = sqrtf(fmaxf(d5sq, 0.f));
  float gap = fmaxf(d5 - d1, 0.f);
  float sc = d1 * (1.f - expf(-gap));
  if (lane == 0) out[q] = sc;
}

extern "C" void kernel_launch(void* const* d_in, const int* in_sizes, int n_in,
                              void* d_out, int out_size, void* d_ws, size_t ws_size,
                              hipStream_t stream) {
  const float* tok = (const float*)d_in[0];   // 3136x768 fp32
  const float* bank = (const float*)d_in[1];  // 65536x768 fp32
  float* out = (float*)d_out;                 // 3136 fp32
  char* ws = (char*)d_ws;
  float* y2 = (float*)ws;                                   // 256KB
  float* x2 = (float*)(ws + 262144);                        // 13KB
  unsigned* cand = (unsigned*)(ws + 1048576);               // 3328*256*5*4 = 17.04MB
  unsigned short* bswz = (unsigned short*)(ws + 18874368);  // 100.66MB
  unsigned short* tswz = (unsigned short*)(ws + 119537664); // 4.87MB
  const size_t WS_NEED = 124649472ull;

  prep_sumsq<<<(MM + QPAD) / 4, 256, 0, stream>>>(tok, bank, y2, x2);
  if (ws_size >= WS_NEED) {
    convert_bank<<<(MM * 96) / 256, 256, 0, stream>>>(bank, bswz);
    convert_tok<<<(QPAD * 96) / 256, 256, 0, stream>>>(tok, tswz);
    gemm_topk<1><<<256, 512, 0, stream>>>(tok, bank, bswz, tswz, y2, x2, cand);
  } else {
    gemm_topk<0><<<256, 512, 0, stream>>>(tok, bank, bswz, tswz, y2, x2, cand);
  }
  merge_rescore<<<NQ / 4, 256, 0, stream>>>(tok, bank, cand, out);
}

// Round 11
// 505.275 us; speedup vs baseline: 12.4774x; 1.2447x over previous
//
#include <hip/hip_runtime.h>

#define NQ      3136
#define QPAD    3328
#define MM      65536
#define CC      768
#define NQB     13
#define KT2N    24              // K-steps per qb (768/32)
#define TT2     (NQB * KT2N)    // 312

typedef short bf16x8 __attribute__((ext_vector_type(8)));
typedef float f32x16 __attribute__((ext_vector_type(16)));
typedef unsigned short u16x4 __attribute__((ext_vector_type(4)));

#define GLOAD16(gp, lp) __builtin_amdgcn_global_load_lds( \
    (const __attribute__((address_space(1))) void*)(gp), \
    (__attribute__((address_space(3))) void*)(lp), 16, 0, 0)

__device__ __forceinline__ unsigned short f2bf(float f) {
  unsigned u = __float_as_uint(f);
  u += 0x7fffu + ((u >> 16) & 1u);
  return (unsigned short)(u >> 16);
}

// 4-slot swizzle (r7/r8: measured 0 bank conflicts with 32-row-span reads)
__device__ __forceinline__ int swz4(int s, int row) {
  return s ^ ((row ^ (row >> 2)) & 3);
}

// ---------------- prep: per-row sum of squares ----------------
__global__ __launch_bounds__(256) void prep_sumsq(const float* __restrict__ tok,
                                                  const float* __restrict__ bank,
                                                  float* __restrict__ y2,
                                                  float* __restrict__ x2) {
  int row = blockIdx.x * 4 + (threadIdx.x >> 6);
  int lane = threadIdx.x & 63;
  const float* src;
  float* dst;
  bool zero = false;
  if (row < MM) {
    src = bank + (size_t)row * CC;
    dst = y2 + row;
  } else {
    int rx = row - MM;
    if (rx >= QPAD) return;
    zero = (rx >= NQ);
    src = tok + (size_t)(zero ? 0 : rx) * CC;
    dst = x2 + rx;
  }
  float s = 0.f;
#pragma unroll
  for (int p = 0; p < 3; ++p) {
    float4 v = *reinterpret_cast<const float4*>(src + (lane + p * 64) * 4);
    s += v.x * v.x + v.y * v.y + v.z * v.z + v.w * v.w;
  }
#pragma unroll
  for (int m = 32; m >= 1; m >>= 1) s += __shfl_xor(s, m, 64);
  if (lane == 0) *dst = zero ? 0.f : s;
}

// ---------------- convert to bf16: [tile=(r>>8)*24+kt2][row][4 slots swz4] ------
__global__ __launch_bounds__(256) void convert_bank(const float* __restrict__ bank,
                                                    unsigned short* __restrict__ dst) {
  unsigned idx = blockIdx.x * 256 + threadIdx.x;   // < 65536*96
  unsigned r = idx / 96;
  unsigned g = idx - r * 96;            // global 8-elem slot in row
  unsigned kt2 = g >> 2, s = g & 3;
  const float* src = bank + (size_t)r * CC + g * 8;
  float4 a = *reinterpret_cast<const float4*>(src);
  float4 b = *reinterpret_cast<const float4*>(src + 4);
  u16x4 p0, p1;
  p0[0] = f2bf(a.x); p0[1] = f2bf(a.y); p0[2] = f2bf(a.z); p0[3] = f2bf(a.w);
  p1[0] = f2bf(b.x); p1[1] = f2bf(b.y); p1[2] = f2bf(b.z); p1[3] = f2bf(b.w);
  unsigned tile = (r >> 8) * KT2N + kt2;
  unsigned row = r & 255;
  unsigned short* d = dst + ((size_t)tile << 13) + row * 32 + (swz4(s, row) << 3);
  *reinterpret_cast<u16x4*>(d) = p0;
  *reinterpret_cast<u16x4*>(d + 4) = p1;
}

__global__ __launch_bounds__(256) void convert_tok(const float* __restrict__ tok,
                                                   unsigned short* __restrict__ dst) {
  unsigned idx = blockIdx.x * 256 + threadIdx.x;   // < 3328*96
  unsigned r = idx / 96;
  unsigned g = idx - r * 96;
  unsigned kt2 = g >> 2, s = g & 3;
  unsigned rs = r < NQ ? r : NQ - 1;
  const float* src = tok + (size_t)rs * CC + g * 8;
  float4 a = *reinterpret_cast<const float4*>(src);
  float4 b = *reinterpret_cast<const float4*>(src + 4);
  u16x4 p0, p1;
  p0[0] = f2bf(a.x); p0[1] = f2bf(a.y); p0[2] = f2bf(a.z); p0[3] = f2bf(a.w);
  p1[0] = f2bf(b.x); p1[1] = f2bf(b.y); p1[2] = f2bf(b.z); p1[3] = f2bf(b.w);
  unsigned tile = (r >> 8) * KT2N + kt2;
  unsigned row = r & 255;
  unsigned short* d = dst + ((size_t)tile << 13) + row * 32 + (swz4(s, row) << 3);
  *reinterpret_cast<u16x4*>(d) = p0;
  *reinterpret_cast<u16x4*>(d + 4) = p1;
}

// ---------------- fused distance-GEMM + per-query top-5 ----------------
// 256 blocks, block b owns mtile b; flat 312 BK32 K-tiles (13 qb x 24).
// 3-slot LDS ring; stage tile t+2 during window t. m201 phase micro-order:
// {12 ds_reads burst; stage; s_barrier; per-wave lgkmcnt(0); setprio+16 MFMA;
//  vmcnt(4); s_barrier} -> waves stagger on the LDS FIFO, MFMA overlaps reads.
template <int PRE>
__global__ __launch_bounds__(512, 2) void gemm_topk(
    const float* __restrict__ tok, const float* __restrict__ bank,
    const unsigned short* __restrict__ bswz, const unsigned short* __restrict__ tswz,
    const float* __restrict__ y2g, const float* __restrict__ x2g,
    unsigned* __restrict__ cand) {
  __shared__ __align__(16) char sA[3][16384];    // Y ring (bank rows)
  __shared__ __align__(16) char sB[3][16384];    // X ring (queries)
  __shared__ float y2s[256];
  __shared__ unsigned fscratch[256 * 5];

  int b = blockIdx.x;          // == mtile
  int tid = threadIdx.x;
  int lane = tid & 63;
  int wid = tid >> 6;
  int wq = wid & 3;            // 64-query strip
  int wm = wid >> 2;           // 128-row m strip
  int l31 = lane & 31;
  int lhi = lane >> 5;

  // per-thread LDS byte offsets within a 16KB slot
  int offA[4][2], offB[2][2];
#pragma unroll
  for (int mi = 0; mi < 4; ++mi)
#pragma unroll
    for (int ks = 0; ks < 2; ++ks) {
      int row = wm * 128 + mi * 32 + l31;
      offA[mi][ks] = row * 64 + swz4(ks * 2 + lhi, row) * 16;
    }
#pragma unroll
  for (int qj = 0; qj < 2; ++qj)
#pragma unroll
    for (int ks = 0; ks < 2; ++ks) {
      int row = wq * 64 + qj * 32 + l31;
      offB[qj][ks] = row * 64 + swz4(ks * 2 + lhi, row) * 16;
    }

  float thrp[2];
  auto set_thr = [&](int qb) {
#pragma unroll
    for (int qj = 0; qj < 2; ++qj) {
      int qg = qb * 256 + wq * 64 + qj * 32 + l31;
      int qgc = qg < NQ ? qg : NQ - 1;
      float x2q = x2g[qgc];
      thrp[qj] = 768.f - 3.f * sqrtf(1536.f + 4.f * x2q);
    }
  };

  float lv[2][5];
  unsigned li[2][5];
#pragma unroll
  for (int qj = 0; qj < 2; ++qj)
#pragma unroll
    for (int s = 0; s < 5; ++s) { lv[qj][s] = 3.4e38f; li[qj][s] = 0u; }

  f32x16 acc[4][2];
#pragma unroll
  for (int mi = 0; mi < 4; ++mi)
#pragma unroll
    for (int qj = 0; qj < 2; ++qj)
#pragma unroll
      for (int e = 0; e < 16; ++e) acc[mi][qj][e] = 0.f;

  auto insert_pass = [&]() {
#pragma unroll
    for (int mi = 0; mi < 4; ++mi) {
#pragma unroll
      for (int r = 0; r < 16; ++r) {
        int mloc = wm * 128 + mi * 32 + (r & 3) + ((r >> 2) << 3) + (lhi << 2);
        float y2v = y2s[mloc];
#pragma unroll
        for (int qj = 0; qj < 2; ++qj) {
          float d2p = fmaf(-2.f, acc[mi][qj][r], y2v);
          if (d2p < thrp[qj] && d2p < lv[qj][4]) {
            float v = d2p;
            unsigned idv = (unsigned)mloc;
#pragma unroll
            for (int s = 0; s < 5; ++s) {
              bool less = v < lv[qj][s];
              float tv = lv[qj][s]; unsigned ti = li[qj][s];
              if (less) { lv[qj][s] = v; li[qj][s] = idv; v = tv; idv = ti; }
            }
          }
        }
#pragma unroll
        for (int qj = 0; qj < 2; ++qj) acc[mi][qj][r] = 0.f;
      }
    }
  };

  auto flushq = [&](int qb) {
#pragma unroll
    for (int qj = 0; qj < 2; ++qj) {
      float ov[5];
      unsigned oi[5];
#pragma unroll
      for (int j = 0; j < 5; ++j) {
        ov[j] = __shfl_xor(lv[qj][j], 32, 64);
        oi[j] = (unsigned)__shfl_xor((int)li[qj][j], 32, 64);
      }
#pragma unroll
      for (int j = 0; j < 5; ++j) {
        float v = ov[j];
        unsigned idv = oi[j];
#pragma unroll
        for (int s = 0; s < 5; ++s) {
          bool less = v < lv[qj][s];
          float tv = lv[qj][s]; unsigned ti = li[qj][s];
          if (less) { lv[qj][s] = v; li[qj][s] = idv; v = tv; idv = ti; }
        }
      }
    }
    unsigned pk[2][5];
#pragma unroll
    for (int qj = 0; qj < 2; ++qj)
#pragma unroll
      for (int s = 0; s < 5; ++s)
        pk[qj][s] = (lv[qj][s] >= 3.0e38f) ? 0xFFFFFFFFu
                    : ((__float_as_uint(fmaxf(lv[qj][s], 0.f)) & 0xFFFFFF00u) | li[qj][s]);
    if (wm == 1 && lhi == 0) {
#pragma unroll
      for (int qj = 0; qj < 2; ++qj) {
        int ql = wq * 64 + qj * 32 + l31;
#pragma unroll
        for (int s = 0; s < 5; ++s) fscratch[ql * 5 + s] = pk[qj][s];
      }
    }
    __syncthreads();
    if (wm == 0 && lhi == 0) {
#pragma unroll
      for (int qj = 0; qj < 2; ++qj) {
        int ql = wq * 64 + qj * 32 + l31;
#pragma unroll
        for (int j = 0; j < 5; ++j) {
          unsigned v = fscratch[ql * 5 + j];
#pragma unroll
          for (int s = 0; s < 5; ++s) {
            unsigned tv = pk[qj][s];
            bool less = v < tv;
            if (less) { pk[qj][s] = v; v = tv; }
          }
        }
        size_t qg = (size_t)(qb * 256 + ql);
        unsigned* cp = cand + (qg * 256 + b) * 5;
#pragma unroll
        for (int s = 0; s < 5; ++s) cp[s] = pk[qj][s];
      }
    }
#pragma unroll
    for (int qj = 0; qj < 2; ++qj)
#pragma unroll
      for (int s = 0; s < 5; ++s) { lv[qj][s] = 3.4e38f; li[qj][s] = 0u; }
  };

  if (tid < 256) y2s[tid] = y2g[b * 256 + tid];
  set_thr(0);

  if constexpr (PRE) {
    auto stageT = [&](int t2, int slot) {
      int kt = t2 % KT2N;
      const char* gA = (const char*)bswz + ((size_t)(b * KT2N + kt) << 14);
      GLOAD16(gA + (tid << 4), &sA[slot][tid << 4]);
      GLOAD16(gA + 8192 + (tid << 4), &sA[slot][8192 + (tid << 4)]);
      const char* gB = (const char*)tswz + ((size_t)t2 << 14);
      GLOAD16(gB + (tid << 4), &sB[slot][tid << 4]);
      GLOAD16(gB + 8192 + (tid << 4), &sB[slot][8192 + (tid << 4)]);
    };
    // prologue: tiles 0,1 -> slots 0,1; wait tile 0 (4 outstanding = tile 1)
    stageT(0, 0);
    stageT(1, 1);
    asm volatile("s_waitcnt vmcnt(4)" ::: "memory");
    __builtin_amdgcn_s_barrier();

    int kt2c = 0, qbc = 0;
    for (int tb = 0; tb < TT2 / 3; ++tb) {
#pragma unroll
      for (int u = 0; u < 3; ++u) {
        int t = tb * 3 + u;                  // ring slot == u (312 = 104*3)
        // ---- phase: burst-issue 12 ds_reads for tile t, then stage t+2 ----
        bf16x8 af[4][2], bf[2][2];
#pragma unroll
        for (int qj = 0; qj < 2; ++qj)
#pragma unroll
          for (int ks = 0; ks < 2; ++ks)
            bf[qj][ks] = *reinterpret_cast<const bf16x8*>(&sB[u][offB[qj][ks]]);
#pragma unroll
        for (int mi = 0; mi < 4; ++mi)
#pragma unroll
          for (int ks = 0; ks < 2; ++ks)
            af[mi][ks] = *reinterpret_cast<const bf16x8*>(&sA[u][offA[mi][ks]]);
        int t2 = t + 2 < TT2 ? t + 2 : TT2 - 1;
        stageT(t2, (u + 2) % 3);
        __builtin_amdgcn_sched_barrier(0);
        __builtin_amdgcn_s_barrier();
        // per-wave drain of own reads -> waves stagger on LDS FIFO order
        asm volatile("s_waitcnt lgkmcnt(0)" ::: "memory");
        __builtin_amdgcn_sched_barrier(0);
        __builtin_amdgcn_s_setprio(1);
#pragma unroll
        for (int ks = 0; ks < 2; ++ks)
#pragma unroll
          for (int mi = 0; mi < 4; ++mi) {
            acc[mi][0] = __builtin_amdgcn_mfma_f32_32x32x16_bf16(af[mi][ks], bf[0][ks], acc[mi][0], 0, 0, 0);
            acc[mi][1] = __builtin_amdgcn_mfma_f32_32x32x16_bf16(af[mi][ks], bf[1][ks], acc[mi][1], 0, 0, 0);
          }
        __builtin_amdgcn_s_setprio(0);
        // counted: stage(t+2) may stay in flight; stage(t+1) complete
        asm volatile("s_waitcnt vmcnt(4)" ::: "memory");
        __builtin_amdgcn_s_barrier();
        // ---- bookkeeping / top-k ----
        if (kt2c == 23) {
          insert_pass();
          flushq(qbc);
          if (qbc + 1 < NQB) set_thr(qbc + 1);
          kt2c = 0; ++qbc;
        } else {
          ++kt2c;
        }
      }
    }
  } else {
    // fallback: stage fp32->bf16 by VALU each step, plain 2-barrier loop
    int kt2c = 0, qbc = 0;
    for (int t = 0; t < TT2; ++t) {
      __syncthreads();
#pragma unroll
      for (int j = 0; j < 2; ++j) {
        int u = tid * 2 + j;
        int row = u >> 2, s = u & 3;
        const float* srcA = bank + (size_t)(b * 256 + row) * CC + kt2c * 32 + s * 8;
        float4 a = *reinterpret_cast<const float4*>(srcA);
        float4 b4 = *reinterpret_cast<const float4*>(srcA + 4);
        u16x4 p0, p1;
        p0[0] = f2bf(a.x); p0[1] = f2bf(a.y); p0[2] = f2bf(a.z); p0[3] = f2bf(a.w);
        p1[0] = f2bf(b4.x); p1[1] = f2bf(b4.y); p1[2] = f2bf(b4.z); p1[3] = f2bf(b4.w);
        char* d = &sA[0][row * 64 + swz4(s, row) * 16];
        *reinterpret_cast<u16x4*>(d) = p0;
        *reinterpret_cast<u16x4*>(d + 8) = p1;
        int srow = qbc * 256 + row;
        srow = srow < NQ ? srow : NQ - 1;
        const float* srcB = tok + (size_t)srow * CC + kt2c * 32 + s * 8;
        a = *reinterpret_cast<const float4*>(srcB);
        b4 = *reinterpret_cast<const float4*>(srcB + 4);
        p0[0] = f2bf(a.x); p0[1] = f2bf(a.y); p0[2] = f2bf(a.z); p0[3] = f2bf(a.w);
        p1[0] = f2bf(b4.x); p1[1] = f2bf(b4.y); p1[2] = f2bf(b4.z); p1[3] = f2bf(b4.w);
        d = &sB[0][row * 64 + swz4(s, row) * 16];
        *reinterpret_cast<u16x4*>(d) = p0;
        *reinterpret_cast<u16x4*>(d + 8) = p1;
      }
      __syncthreads();
      bf16x8 af[4][2], bf[2][2];
#pragma unroll
      for (int qj = 0; qj < 2; ++qj)
#pragma unroll
        for (int ks = 0; ks < 2; ++ks)
          bf[qj][ks] = *reinterpret_cast<const bf16x8*>(&sB[0][offB[qj][ks]]);
#pragma unroll
      for (int mi = 0; mi < 4; ++mi)
#pragma unroll
        for (int ks = 0; ks < 2; ++ks)
          af[mi][ks] = *reinterpret_cast<const bf16x8*>(&sA[0][offA[mi][ks]]);
#pragma unroll
      for (int ks = 0; ks < 2; ++ks)
#pragma unroll
        for (int mi = 0; mi < 4; ++mi) {
          acc[mi][0] = __builtin_amdgcn_mfma_f32_32x32x16_bf16(af[mi][ks], bf[0][ks], acc[mi][0], 0, 0, 0);
          acc[mi][1] = __builtin_amdgcn_mfma_f32_32x32x16_bf16(af[mi][ks], bf[1][ks], acc[mi][1], 0, 0, 0);
        }
      if (kt2c == 23) {
        __syncthreads();
        insert_pass();
        flushq(qbc);
        if (qbc + 1 < NQB) set_thr(qbc + 1);
        kt2c = 0; ++qbc;
      } else {
        ++kt2c;
      }
    }
  }
}

// ---------------- merge candidates, exact fp32 rescoring, final score ----------------
__global__ __launch_bounds__(256) void merge_rescore(
    const float* __restrict__ tok, const float* __restrict__ bank,
    const unsigned* __restrict__ cand, float* __restrict__ out) {
  int q = blockIdx.x * 4 + (threadIdx.x >> 6);
  int lane = threadIdx.x & 63;
  const unsigned* cp = cand + (size_t)q * 1280;
  unsigned e[20];   // 4 blocks x 5 entries per lane
#pragma unroll
  for (int j = 0; j < 20; ++j) e[j] = cp[lane * 20 + j];
  unsigned gids[8];
#pragma unroll
  for (int r = 0; r < 8; ++r) {
    unsigned bv = e[0];
#pragma unroll
    for (int j = 1; j < 20; ++j) bv = e[j] < bv ? e[j] : bv;
    unsigned rv = bv;
    int rl = lane;
#pragma unroll
    for (int m = 32; m >= 1; m >>= 1) {
      unsigned ov = (unsigned)__shfl_xor((int)rv, m, 64);
      int ol = __shfl_xor(rl, m, 64);
      if (ov < rv || (ov == rv && ol < rl)) { rv = ov; rl = ol; }
    }
    unsigned gid = 0;
    if (lane == rl) {
      bool done = false;
#pragma unroll
      for (int j = 0; j < 20; ++j) {
        if (!done && e[j] == rv) {
          gid = (unsigned)((lane * 4 + j / 5) * 256) + (e[j] & 255u);
          e[j] = 0xFFFFFFFFu;
          done = true;
        }
      }
    }
    gids[r] = (unsigned)__shfl((int)gid, rl, 64);
  }
  float xv[12];
  {
    const float* xp = tok + (size_t)q * CC + lane * 12;
    float4 a = *reinterpret_cast<const float4*>(xp);
    float4 bq = *reinterpret_cast<const float4*>(xp + 4);
    float4 cc4 = *reinterpret_cast<const float4*>(xp + 8);
    xv[0] = a.x; xv[1] = a.y; xv[2] = a.z; xv[3] = a.w;
    xv[4] = bq.x; xv[5] = bq.y; xv[6] = bq.z; xv[7] = bq.w;
    xv[8] = cc4.x; xv[9] = cc4.y; xv[10] = cc4.z; xv[11] = cc4.w;
  }
  float d2e[8];
#pragma unroll
  for (int r = 0; r < 8; ++r) {
    const float* yp = bank + (size_t)(gids[r] & (MM - 1)) * CC + lane * 12;
    float4 a = *reinterpret_cast<const float4*>(yp);
    float4 bq = *reinterpret_cast<const float4*>(yp + 4);
    float4 cc4 = *reinterpret_cast<const float4*>(yp + 8);
    float yv[12];
    yv[0] = a.x; yv[1] = a.y; yv[2] = a.z; yv[3] = a.w;
    yv[4] = bq.x; yv[5] = bq.y; yv[6] = bq.z; yv[7] = bq.w;
    yv[8] = cc4.x; yv[9] = cc4.y; yv[10] = cc4.z; yv[11] = cc4.w;
    float s = 0.f;
#pragma unroll
    for (int e2 = 0; e2 < 12; ++e2) {
      float d = xv[e2] - yv[e2];
      s = fmaf(d, d, s);
    }
#pragma unroll
    for (int m = 32; m >= 1; m >>= 1) s += __shfl_xor(s, m, 64);
    d2e[r] = s;
  }
  float d1sq = 0.f, d5sq = 0.f;
#pragma unroll
  for (int r5 = 0; r5 < 5; ++r5) {
    float bv = d2e[0];
    int bj = 0;
#pragma unroll
    for (int j = 1; j < 8; ++j)
      if (d2e[j] < bv) { bv = d2e[j]; bj = j; }
    if (r5 == 0) d1sq = bv;
    if (r5 == 4) d5sq = bv;
#pragma unroll
    for (int j = 0; j < 8; ++j)
      if (j == bj) d2e[j] = 3.4e38f;
  }
  float d1 = sqrtf(fmaxf(d1sq, 0.f));
  float d5 = sqrtf(fmaxf(d5sq, 0.f));
  float gap = fmaxf(d5 - d1, 0.f);
  float sc = d1 * (1.f - expf(-gap));
  if (lane == 0) out[q] = sc;
}

extern "C" void kernel_launch(void* const* d_in, const int* in_sizes, int n_in,
                              void* d_out, int out_size, void* d_ws, size_t ws_size,
                              hipStream_t stream) {
  const float* tok = (const float*)d_in[0];   // 3136x768 fp32
  const float* bank = (const float*)d_in[1];  // 65536x768 fp32
  float* out = (float*)d_out;                 // 3136 fp32
  char* ws = (char*)d_ws;
  float* y2 = (float*)ws;                                   // 256KB
  float* x2 = (float*)(ws + 262144);                        // 13KB
  unsigned* cand = (unsigned*)(ws + 1048576);               // 3328*256*5*4 = 17.04MB
  unsigned short* bswz = (unsigned short*)(ws + 18874368);  // 100.66MB
  unsigned short* tswz = (unsigned short*)(ws + 119537664); // 4.87MB
  const size_t WS_NEED = 124649472ull;

  prep_sumsq<<<(MM + QPAD) / 4, 256, 0, stream>>>(tok, bank, y2, x2);
  if (ws_size >= WS_NEED) {
    convert_bank<<<(MM * 96) / 256, 256, 0, stream>>>(bank, bswz);
    convert_tok<<<(QPAD * 96) / 256, 256, 0, stream>>>(tok, tswz);
    gemm_topk<1><<<256, 512, 0, stream>>>(tok, bank, bswz, tswz, y2, x2, cand);
  } else {
    gemm_topk<0><<<256, 512, 0, stream>>>(tok, bank, bswz, tswz, y2, x2, cand);
  }
  merge_rescore<<<NQ / 4, 256, 0, stream>>>(tok, bank, cand, out);
}

// Round 13
// 399.486 us; speedup vs baseline: 15.7815x; 1.2648x over previous
//
#include <hip/hip_runtime.h>

#define NQ      3136
#define QPAD    3328
#define MM      65536
#define CC      768
#define NQB     13
#define KTILES  12              // BK64 tiles per qb
#define TT      (NQB * KTILES)  // 156

typedef int   i32x4v __attribute__((ext_vector_type(4)));
typedef int   i32x8v __attribute__((ext_vector_type(8)));
typedef float f32x16 __attribute__((ext_vector_type(16)));

#define GLOAD16(gp, lp) __builtin_amdgcn_global_load_lds( \
    (const __attribute__((address_space(1))) void*)(gp), \
    (__attribute__((address_space(3))) void*)(lp), 16, 0, 0)

// 4-slot swizzle (r7/r8/r11: measured 0 bank conflicts, 32-row-span + lhi-split reads)
__device__ __forceinline__ int swz4(int s, int row) {
  return s ^ ((row ^ (row >> 2)) & 3);
}

// pack 16 fp32 -> 16 fp8 e4m3 bytes (4 dwords)
__device__ __forceinline__ i32x4v pk16(float4 f0, float4 f1, float4 f2, float4 f3) {
  i32x4v w;
  int t;
  t = __builtin_amdgcn_cvt_pk_fp8_f32(f0.x, f0.y, 0, false);
  w[0] = __builtin_amdgcn_cvt_pk_fp8_f32(f0.z, f0.w, t, true);
  t = __builtin_amdgcn_cvt_pk_fp8_f32(f1.x, f1.y, 0, false);
  w[1] = __builtin_amdgcn_cvt_pk_fp8_f32(f1.z, f1.w, t, true);
  t = __builtin_amdgcn_cvt_pk_fp8_f32(f2.x, f2.y, 0, false);
  w[2] = __builtin_amdgcn_cvt_pk_fp8_f32(f2.z, f2.w, t, true);
  t = __builtin_amdgcn_cvt_pk_fp8_f32(f3.x, f3.y, 0, false);
  w[3] = __builtin_amdgcn_cvt_pk_fp8_f32(f3.z, f3.w, t, true);
  return w;
}

// ---------------- prep: per-row sum of squares ----------------
__global__ __launch_bounds__(256) void prep_sumsq(const float* __restrict__ tok,
                                                  const float* __restrict__ bank,
                                                  float* __restrict__ y2,
                                                  float* __restrict__ x2) {
  int row = blockIdx.x * 4 + (threadIdx.x >> 6);
  int lane = threadIdx.x & 63;
  const float* src;
  float* dst;
  bool zero = false;
  if (row < MM) {
    src = bank + (size_t)row * CC;
    dst = y2 + row;
  } else {
    int rx = row - MM;
    if (rx >= QPAD) return;
    zero = (rx >= NQ);
    src = tok + (size_t)(zero ? 0 : rx) * CC;
    dst = x2 + rx;
  }
  float s = 0.f;
#pragma unroll
  for (int p = 0; p < 3; ++p) {
    float4 v = *reinterpret_cast<const float4*>(src + (lane + p * 64) * 4);
    s += v.x * v.x + v.y * v.y + v.z * v.z + v.w * v.w;
  }
#pragma unroll
  for (int m = 32; m >= 1; m >>= 1) s += __shfl_xor(s, m, 64);
  if (lane == 0) *dst = zero ? 0.f : s;
}

// ---------------- convert fp32 -> fp8 e4m3, tile-major pre-swizzled ----------------
// tile = (r>>8)*12 + kt64 (16KB each): [row 256][4 slots of 16B, slot s at swz4(s,row)]
__global__ __launch_bounds__(256) void convert_bank_fp8(const float* __restrict__ bank,
                                                        unsigned char* __restrict__ dst) {
  unsigned idx = blockIdx.x * 256 + threadIdx.x;   // < 65536*48
  unsigned r = idx / 48;
  unsigned rem = idx - r * 48;
  unsigned kt = rem >> 2, s = rem & 3;
  const float* src = bank + (size_t)r * CC + kt * 64 + s * 16;
  float4 f0 = *reinterpret_cast<const float4*>(src);
  float4 f1 = *reinterpret_cast<const float4*>(src + 4);
  float4 f2 = *reinterpret_cast<const float4*>(src + 8);
  float4 f3 = *reinterpret_cast<const float4*>(src + 12);
  i32x4v w = pk16(f0, f1, f2, f3);
  unsigned tile = (r >> 8) * 12 + kt;
  unsigned row = r & 255;
  *reinterpret_cast<i32x4v*>(dst + ((size_t)tile << 14) + row * 64 + swz4(s, row) * 16) = w;
}

__global__ __launch_bounds__(256) void convert_tok_fp8(const float* __restrict__ tok,
                                                       unsigned char* __restrict__ dst) {
  unsigned idx = blockIdx.x * 256 + threadIdx.x;   // < 3328*48
  unsigned r = idx / 48;
  unsigned rem = idx - r * 48;
  unsigned kt = rem >> 2, s = rem & 3;
  unsigned rs = r < NQ ? r : NQ - 1;
  const float* src = tok + (size_t)rs * CC + kt * 64 + s * 16;
  float4 f0 = *reinterpret_cast<const float4*>(src);
  float4 f1 = *reinterpret_cast<const float4*>(src + 4);
  float4 f2 = *reinterpret_cast<const float4*>(src + 8);
  float4 f3 = *reinterpret_cast<const float4*>(src + 12);
  i32x4v w = pk16(f0, f1, f2, f3);
  unsigned tile = (r >> 8) * 12 + kt;
  unsigned row = r & 255;
  *reinterpret_cast<i32x4v*>(dst + ((size_t)tile << 14) + row * 64 + swz4(s, row) * 16) = w;
}

// ---------------- fused distance-GEMM (fp8) + per-query top-5 ----------------
// 256 blocks, block b owns mtile b; flat 156 BK64 tiles (13 qb x 12).
// 3-slot LDS ring (16KB A + 16KB B per slot); stage t+2 ahead; counted vmcnt(4);
// per tile: 12 ds_read_b128 + 4 gload + 8 mfma_scale_32x32x64_fp8 (scale=1.0).
template <int PRE>
__global__ __launch_bounds__(512, 2) void gemm_topk(
    const float* __restrict__ tok, const float* __restrict__ bank,
    const unsigned char* __restrict__ bf8, const unsigned char* __restrict__ tf8,
    const float* __restrict__ y2g, const float* __restrict__ x2g,
    unsigned* __restrict__ cand) {
  __shared__ __align__(16) char sA[3][16384];    // Y ring (bank rows, fp8)
  __shared__ __align__(16) char sB[3][16384];    // X ring (queries, fp8)
  __shared__ float y2s[256];
  __shared__ unsigned fscratch[256 * 5];

  int b = blockIdx.x;          // == mtile
  int tid = threadIdx.x;
  int lane = tid & 63;
  int wid = tid >> 6;
  int wq = wid & 3;            // 64-query strip
  int wm = wid >> 2;           // 128-row m strip
  int l31 = lane & 31;
  int lhi = lane >> 5;

  // per-thread LDS byte offsets within a 16KB slot (2 x b128 per 32B frag)
  int offA[4][2], offB[2][2];
#pragma unroll
  for (int mi = 0; mi < 4; ++mi)
#pragma unroll
    for (int j = 0; j < 2; ++j) {
      int row = wm * 128 + mi * 32 + l31;
      offA[mi][j] = row * 64 + swz4(lhi * 2 + j, row) * 16;
    }
#pragma unroll
  for (int qj = 0; qj < 2; ++qj)
#pragma unroll
    for (int j = 0; j < 2; ++j) {
      int row = wq * 64 + qj * 32 + l31;
      offB[qj][j] = row * 64 + swz4(lhi * 2 + j, row) * 16;
    }

  float thrp[2];
  auto set_thr = [&](int qb) {
#pragma unroll
    for (int qj = 0; qj < 2; ++qj) {
      int qg = qb * 256 + wq * 64 + qj * 32 + l31;
      int qgc = qg < NQ ? qg : NQ - 1;
      float x2q = x2g[qgc];
      thrp[qj] = 768.f - 3.f * sqrtf(1536.f + 4.f * x2q);
    }
  };

  float lv[2][5];
  unsigned li[2][5];
#pragma unroll
  for (int qj = 0; qj < 2; ++qj)
#pragma unroll
    for (int s = 0; s < 5; ++s) { lv[qj][s] = 3.4e38f; li[qj][s] = 0u; }

  f32x16 acc[4][2];
#pragma unroll
  for (int mi = 0; mi < 4; ++mi)
#pragma unroll
    for (int qj = 0; qj < 2; ++qj)
#pragma unroll
      for (int e = 0; e < 16; ++e) acc[mi][qj][e] = 0.f;

  auto insert_pass = [&]() {
#pragma unroll
    for (int mi = 0; mi < 4; ++mi) {
#pragma unroll
      for (int r = 0; r < 16; ++r) {
        int mloc = wm * 128 + mi * 32 + (r & 3) + ((r >> 2) << 3) + (lhi << 2);
        float y2v = y2s[mloc];
#pragma unroll
        for (int qj = 0; qj < 2; ++qj) {
          float d2p = fmaf(-2.f, acc[mi][qj][r], y2v);
          if (d2p < thrp[qj] && d2p < lv[qj][4]) {
            float v = d2p;
            unsigned idv = (unsigned)mloc;
#pragma unroll
            for (int s = 0; s < 5; ++s) {
              bool less = v < lv[qj][s];
              float tv = lv[qj][s]; unsigned ti = li[qj][s];
              if (less) { lv[qj][s] = v; li[qj][s] = idv; v = tv; idv = ti; }
            }
          }
        }
#pragma unroll
        for (int qj = 0; qj < 2; ++qj) acc[mi][qj][r] = 0.f;
      }
    }
  };

  auto flushq = [&](int qb) {
#pragma unroll
    for (int qj = 0; qj < 2; ++qj) {
      float ov[5];
      unsigned oi[5];
#pragma unroll
      for (int j = 0; j < 5; ++j) {
        ov[j] = __shfl_xor(lv[qj][j], 32, 64);
        oi[j] = (unsigned)__shfl_xor((int)li[qj][j], 32, 64);
      }
#pragma unroll
      for (int j = 0; j < 5; ++j) {
        float v = ov[j];
        unsigned idv = oi[j];
#pragma unroll
        for (int s = 0; s < 5; ++s) {
          bool less = v < lv[qj][s];
          float tv = lv[qj][s]; unsigned ti = li[qj][s];
          if (less) { lv[qj][s] = v; li[qj][s] = idv; v = tv; idv = ti; }
        }
      }
    }
    unsigned pk[2][5];
#pragma unroll
    for (int qj = 0; qj < 2; ++qj)
#pragma unroll
      for (int s = 0; s < 5; ++s)
        pk[qj][s] = (lv[qj][s] >= 3.0e38f) ? 0xFFFFFFFFu
                    : ((__float_as_uint(fmaxf(lv[qj][s], 0.f)) & 0xFFFFFF00u) | li[qj][s]);
    if (wm == 1 && lhi == 0) {
#pragma unroll
      for (int qj = 0; qj < 2; ++qj) {
        int ql = wq * 64 + qj * 32 + l31;
#pragma unroll
        for (int s = 0; s < 5; ++s) fscratch[ql * 5 + s] = pk[qj][s];
      }
    }
    __syncthreads();
    if (wm == 0 && lhi == 0) {
#pragma unroll
      for (int qj = 0; qj < 2; ++qj) {
        int ql = wq * 64 + qj * 32 + l31;
#pragma unroll
        for (int j = 0; j < 5; ++j) {
          unsigned v = fscratch[ql * 5 + j];
#pragma unroll
          for (int s = 0; s < 5; ++s) {
            unsigned tv = pk[qj][s];
            bool less = v < tv;
            if (less) { pk[qj][s] = v; v = tv; }
          }
        }
        size_t qg = (size_t)(qb * 256 + ql);
        unsigned* cp = cand + (qg * 256 + b) * 5;
#pragma unroll
        for (int s = 0; s < 5; ++s) cp[s] = pk[qj][s];
      }
    }
#pragma unroll
    for (int qj = 0; qj < 2; ++qj)
#pragma unroll
      for (int s = 0; s < 5; ++s) { lv[qj][s] = 3.4e38f; li[qj][s] = 0u; }
  };

  auto do_mfma = [&](int u) {
    i32x8v aV[4], bV[2];
#pragma unroll
    for (int qj = 0; qj < 2; ++qj) {
      i32x4v lo = *reinterpret_cast<const i32x4v*>(&sB[u][offB[qj][0]]);
      i32x4v hi = *reinterpret_cast<const i32x4v*>(&sB[u][offB[qj][1]]);
      bV[qj] = __builtin_shufflevector(lo, hi, 0, 1, 2, 3, 4, 5, 6, 7);
    }
#pragma unroll
    for (int mi = 0; mi < 4; ++mi) {
      i32x4v lo = *reinterpret_cast<const i32x4v*>(&sA[u][offA[mi][0]]);
      i32x4v hi = *reinterpret_cast<const i32x4v*>(&sA[u][offA[mi][1]]);
      aV[mi] = __builtin_shufflevector(lo, hi, 0, 1, 2, 3, 4, 5, 6, 7);
    }
    __builtin_amdgcn_s_setprio(1);
#pragma unroll
    for (int mi = 0; mi < 4; ++mi) {
      acc[mi][0] = __builtin_amdgcn_mfma_scale_f32_32x32x64_f8f6f4(
          aV[mi], bV[0], acc[mi][0], 0, 0, 0, 0x7F7F7F7F, 0, 0x7F7F7F7F);
      acc[mi][1] = __builtin_amdgcn_mfma_scale_f32_32x32x64_f8f6f4(
          aV[mi], bV[1], acc[mi][1], 0, 0, 0, 0x7F7F7F7F, 0, 0x7F7F7F7F);
    }
    __builtin_amdgcn_s_setprio(0);
  };

  if (tid < 256) y2s[tid] = y2g[b * 256 + tid];
  set_thr(0);

  if constexpr (PRE) {
    auto stageT = [&](int t2, int slot) {
      int kt = t2 % KTILES;
      const char* gA = (const char*)bf8 + ((size_t)(b * KTILES + kt) << 14);
      GLOAD16(gA + (tid << 4), &sA[slot][tid << 4]);
      GLOAD16(gA + 8192 + (tid << 4), &sA[slot][8192 + (tid << 4)]);
      const char* gB = (const char*)tf8 + ((size_t)t2 << 14);
      GLOAD16(gB + (tid << 4), &sB[slot][tid << 4]);
      GLOAD16(gB + 8192 + (tid << 4), &sB[slot][8192 + (tid << 4)]);
    };
    stageT(0, 0);
    stageT(1, 1);
    asm volatile("s_waitcnt vmcnt(4)" ::: "memory");
    __builtin_amdgcn_s_barrier();

    int ktc = 0, qbc = 0;
    for (int tb = 0; tb < TT / 3; ++tb) {
#pragma unroll
      for (int u = 0; u < 3; ++u) {
        int t = tb * 3 + u;                  // ring slot == u (156 = 52*3)
        int t2 = t + 2 < TT ? t + 2 : TT - 1;
        stageT(t2, (u + 2) % 3);
        do_mfma(u);
        asm volatile("s_waitcnt vmcnt(4)" ::: "memory");
        __builtin_amdgcn_sched_barrier(0);
        __builtin_amdgcn_s_barrier();
        if (ktc == KTILES - 1) {
          insert_pass();
          flushq(qbc);
          if (qbc + 1 < NQB) set_thr(qbc + 1);
          ktc = 0; ++qbc;
        } else {
          ++ktc;
        }
      }
    }
  } else {
    // fallback: VALU-convert fp32->fp8 into slot 0 each tile
    int ktc = 0, qbc = 0;
    for (int t = 0; t < TT; ++t) {
      __syncthreads();
#pragma unroll
      for (int j = 0; j < 2; ++j) {
        int u = tid * 2 + j;
        int row = u >> 2, s = u & 3;
        const float* srcA = bank + (size_t)(b * 256 + row) * CC + ktc * 64 + s * 16;
        float4 f0 = *reinterpret_cast<const float4*>(srcA);
        float4 f1 = *reinterpret_cast<const float4*>(srcA + 4);
        float4 f2 = *reinterpret_cast<const float4*>(srcA + 8);
        float4 f3 = *reinterpret_cast<const float4*>(srcA + 12);
        *reinterpret_cast<i32x4v*>(&sA[0][row * 64 + swz4(s, row) * 16]) = pk16(f0, f1, f2, f3);
        int qr = qbc * 256 + row;
        qr = qr < NQ ? qr : NQ - 1;
        const float* srcB = tok + (size_t)qr * CC + ktc * 64 + s * 16;
        f0 = *reinterpret_cast<const float4*>(srcB);
        f1 = *reinterpret_cast<const float4*>(srcB + 4);
        f2 = *reinterpret_cast<const float4*>(srcB + 8);
        f3 = *reinterpret_cast<const float4*>(srcB + 12);
        *reinterpret_cast<i32x4v*>(&sB[0][row * 64 + swz4(s, row) * 16]) = pk16(f0, f1, f2, f3);
      }
      __syncthreads();
      do_mfma(0);
      if (ktc == KTILES - 1) {
        __syncthreads();
        insert_pass();
        flushq(qbc);
        if (qbc + 1 < NQB) set_thr(qbc + 1);
        ktc = 0; ++qbc;
      } else {
        ++ktc;
      }
    }
  }
}

// ---------------- merge candidates, exact fp32 rescoring (top-16), final score ----
__global__ __launch_bounds__(256) void merge_rescore(
    const float* __restrict__ tok, const float* __restrict__ bank,
    const unsigned* __restrict__ cand, float* __restrict__ out) {
  int q = blockIdx.x * 4 + (threadIdx.x >> 6);
  int lane = threadIdx.x & 63;
  const unsigned* cp = cand + (size_t)q * 1280;
  unsigned e[20];   // 4 blocks x 5 entries per lane
#pragma unroll
  for (int j = 0; j < 20; ++j) e[j] = cp[lane * 20 + j];
  unsigned gids[16];
#pragma unroll
  for (int r = 0; r < 16; ++r) {
    unsigned bv = e[0];
#pragma unroll
    for (int j = 1; j < 20; ++j) bv = e[j] < bv ? e[j] : bv;
    unsigned rv = bv;
    int rl = lane;
#pragma unroll
    for (int m = 32; m >= 1; m >>= 1) {
      unsigned ov = (unsigned)__shfl_xor((int)rv, m, 64);
      int ol = __shfl_xor(rl, m, 64);
      if (ov < rv || (ov == rv && ol < rl)) { rv = ov; rl = ol; }
    }
    unsigned gid = 0;
    if (lane == rl) {
      bool done = false;
#pragma unroll
      for (int j = 0; j < 20; ++j) {
        if (!done && e[j] == rv) {
          gid = (unsigned)((lane * 4 + j / 5) * 256) + (e[j] & 255u);
          e[j] = 0xFFFFFFFFu;
          done = true;
        }
      }
    }
    gids[r] = (unsigned)__shfl((int)gid, rl, 64);
  }
  float xv[12];
  {
    const float* xp = tok + (size_t)q * CC + lane * 12;
    float4 a = *reinterpret_cast<const float4*>(xp);
    float4 bq = *reinterpret_cast<const float4*>(xp + 4);
    float4 cc4 = *reinterpret_cast<const float4*>(xp + 8);
    xv[0] = a.x; xv[1] = a.y; xv[2] = a.z; xv[3] = a.w;
    xv[4] = bq.x; xv[5] = bq.y; xv[6] = bq.z; xv[7] = bq.w;
    xv[8] = cc4.x; xv[9] = cc4.y; xv[10] = cc4.z; xv[11] = cc4.w;
  }
  float d2e[16];
#pragma unroll
  for (int r = 0; r < 16; ++r) {
    const float* yp = bank + (size_t)(gids[r] & (MM - 1)) * CC + lane * 12;
    float4 a = *reinterpret_cast<const float4*>(yp);
    float4 bq = *reinterpret_cast<const float4*>(yp + 4);
    float4 cc4 = *reinterpret_cast<const float4*>(yp + 8);
    float yv[12];
    yv[0] = a.x; yv[1] = a.y; yv[2] = a.z; yv[3] = a.w;
    yv[4] = bq.x; yv[5] = bq.y; yv[6] = bq.z; yv[7] = bq.w;
    yv[8] = cc4.x; yv[9] = cc4.y; yv[10] = cc4.z; yv[11] = cc4.w;
    float s = 0.f;
#pragma unroll
    for (int e2 = 0; e2 < 12; ++e2) {
      float d = xv[e2] - yv[e2];
      s = fmaf(d, d, s);
    }
#pragma unroll
    for (int m = 32; m >= 1; m >>= 1) s += __shfl_xor(s, m, 64);
    d2e[r] = s;
  }
  float d1sq = 0.f, d5sq = 0.f;
#pragma unroll
  for (int r5 = 0; r5 < 5; ++r5) {
    float bv = d2e[0];
    int bj = 0;
#pragma unroll
    for (int j = 1; j < 16; ++j)
      if (d2e[j] < bv) { bv = d2e[j]; bj = j; }
    if (r5 == 0) d1sq = bv;
    if (r5 == 4) d5sq = bv;
#pragma unroll
    for (int j = 0; j < 16; ++j)
      if (j == bj) d2e[j] = 3.4e38f;
  }
  float d1 = sqrtf(fmaxf(d1sq, 0.f));
  float d5 = sqrtf(fmaxf(d5sq, 0.f));
  float gap = fmaxf(d5 - d1, 0.f);
  float sc = d1 * (1.f - expf(-gap));
  if (lane == 0) out[q] = sc;
}

extern "C" void kernel_launch(void* const* d_in, const int* in_sizes, int n_in,
                              void* d_out, int out_size, void* d_ws, size_t ws_size,
                              hipStream_t stream) {
  const float* tok = (const float*)d_in[0];   // 3136x768 fp32
  const float* bank = (const float*)d_in[1];  // 65536x768 fp32
  float* out = (float*)d_out;                 // 3136 fp32
  char* ws = (char*)d_ws;
  float* y2 = (float*)ws;                                     // 256KB
  float* x2 = (float*)(ws + 262144);                          // 13KB
  unsigned* cand = (unsigned*)(ws + 1048576);                 // 17.04MB
  unsigned char* bf8 = (unsigned char*)(ws + 18874368);       // 50.33MB (fp8 bank tiles)
  unsigned char* tf8 = (unsigned char*)(ws + 69206016);       // 2.56MB (fp8 tok tiles)
  const size_t WS_NEED = 71761920ull;

  prep_sumsq<<<(MM + QPAD) / 4, 256, 0, stream>>>(tok, bank, y2, x2);
  if (ws_size >= WS_NEED) {
    convert_bank_fp8<<<(MM * 48) / 256, 256, 0, stream>>>(bank, bf8);
    convert_tok_fp8<<<(QPAD * 48) / 256, 256, 0, stream>>>(tok, tf8);
    gemm_topk<1><<<256, 512, 0, stream>>>(tok, bank, bf8, tf8, y2, x2, cand);
  } else {
    gemm_topk<0><<<256, 512, 0, stream>>>(tok, bank, bf8, tf8, y2, x2, cand);
  }
  merge_rescore<<<NQ / 4, 256, 0, stream>>>(tok, bank, cand, out);
}

// Round 14
// 337.316 us; speedup vs baseline: 18.6902x; 1.1843x over previous
//
#include <hip/hip_runtime.h>

#define NQ      3136
#define QPAD    3328
#define MM      65536
#define CC      768
#define NQB     13
#define KTILES  12              // BK64 tiles per qb
#define TT      (NQB * KTILES)  // 156

typedef int   i32x4v __attribute__((ext_vector_type(4)));
typedef int   i32x8v __attribute__((ext_vector_type(8)));
typedef float f32x16 __attribute__((ext_vector_type(16)));

#define GLOAD16(gp, lp) __builtin_amdgcn_global_load_lds( \
    (const __attribute__((address_space(1))) void*)(gp), \
    (__attribute__((address_space(3))) void*)(lp), 16, 0, 0)

// 4-slot swizzle (r7/r8/r11/r13: measured 0 bank conflicts)
__device__ __forceinline__ int swz4(int s, int row) {
  return s ^ ((row ^ (row >> 2)) & 3);
}

// pack 16 fp32 -> 16 fp8 e4m3 bytes (4 dwords)
__device__ __forceinline__ i32x4v pk16(float4 f0, float4 f1, float4 f2, float4 f3) {
  i32x4v w;
  int t;
  t = __builtin_amdgcn_cvt_pk_fp8_f32(f0.x, f0.y, 0, false);
  w[0] = __builtin_amdgcn_cvt_pk_fp8_f32(f0.z, f0.w, t, true);
  t = __builtin_amdgcn_cvt_pk_fp8_f32(f1.x, f1.y, 0, false);
  w[1] = __builtin_amdgcn_cvt_pk_fp8_f32(f1.z, f1.w, t, true);
  t = __builtin_amdgcn_cvt_pk_fp8_f32(f2.x, f2.y, 0, false);
  w[2] = __builtin_amdgcn_cvt_pk_fp8_f32(f2.z, f2.w, t, true);
  t = __builtin_amdgcn_cvt_pk_fp8_f32(f3.x, f3.y, 0, false);
  w[3] = __builtin_amdgcn_cvt_pk_fp8_f32(f3.z, f3.w, t, true);
  return w;
}

// ---------------- prep (fallback path only): per-row sum of squares ----------------
__global__ __launch_bounds__(256) void prep_sumsq(const float* __restrict__ tok,
                                                  const float* __restrict__ bank,
                                                  float* __restrict__ y2,
                                                  float* __restrict__ x2) {
  int row = blockIdx.x * 4 + (threadIdx.x >> 6);
  int lane = threadIdx.x & 63;
  const float* src;
  float* dst;
  bool zero = false;
  if (row < MM) {
    src = bank + (size_t)row * CC;
    dst = y2 + row;
  } else {
    int rx = row - MM;
    if (rx >= QPAD) return;
    zero = (rx >= NQ);
    src = tok + (size_t)(zero ? 0 : rx) * CC;
    dst = x2 + rx;
  }
  float s = 0.f;
#pragma unroll
  for (int p = 0; p < 3; ++p) {
    float4 v = *reinterpret_cast<const float4*>(src + (lane + p * 64) * 4);
    s += v.x * v.x + v.y * v.y + v.z * v.z + v.w * v.w;
  }
#pragma unroll
  for (int m = 32; m >= 1; m >>= 1) s += __shfl_xor(s, m, 64);
  if (lane == 0) *dst = zero ? 0.f : s;
}

// ---------------- fused: fp32 -> fp8 e4m3 (tile-major pre-swizzled) + sumsq ----------
// one wave per row; lanes 0-47 each handle 16 elems (16B fp8 chunk); y2 via shfl.
__global__ __launch_bounds__(256) void convert_bank_y2(const float* __restrict__ bank,
                                                       unsigned char* __restrict__ dst,
                                                       float* __restrict__ y2) {
  int row = blockIdx.x * 4 + (threadIdx.x >> 6);
  int lane = threadIdx.x & 63;
  float s = 0.f;
  i32x4v w;
  if (lane < 48) {
    const float* src = bank + (size_t)row * CC + lane * 16;
    float4 f0 = *reinterpret_cast<const float4*>(src);
    float4 f1 = *reinterpret_cast<const float4*>(src + 4);
    float4 f2 = *reinterpret_cast<const float4*>(src + 8);
    float4 f3 = *reinterpret_cast<const float4*>(src + 12);
    s = f0.x*f0.x + f0.y*f0.y + f0.z*f0.z + f0.w*f0.w
      + f1.x*f1.x + f1.y*f1.y + f1.z*f1.z + f1.w*f1.w
      + f2.x*f2.x + f2.y*f2.y + f2.z*f2.z + f2.w*f2.w
      + f3.x*f3.x + f3.y*f3.y + f3.z*f3.z + f3.w*f3.w;
    w = pk16(f0, f1, f2, f3);
  }
#pragma unroll
  for (int m = 32; m >= 1; m >>= 1) s += __shfl_xor(s, m, 64);
  if (lane == 0) y2[row] = s;
  if (lane < 48) {
    unsigned kt = lane >> 2, sl = lane & 3;
    unsigned tile = (unsigned)(row >> 8) * 12 + kt;
    unsigned r8 = row & 255;
    *reinterpret_cast<i32x4v*>(dst + ((size_t)tile << 14) + r8 * 64 + swz4(sl, r8) * 16) = w;
  }
}

__global__ __launch_bounds__(256) void convert_tok_x2(const float* __restrict__ tok,
                                                      unsigned char* __restrict__ dst,
                                                      float* __restrict__ x2) {
  int row = blockIdx.x * 4 + (threadIdx.x >> 6);  // < QPAD
  int lane = threadIdx.x & 63;
  int rs = row < NQ ? row : NQ - 1;
  float s = 0.f;
  i32x4v w;
  if (lane < 48) {
    const float* src = tok + (size_t)rs * CC + lane * 16;
    float4 f0 = *reinterpret_cast<const float4*>(src);
    float4 f1 = *reinterpret_cast<const float4*>(src + 4);
    float4 f2 = *reinterpret_cast<const float4*>(src + 8);
    float4 f3 = *reinterpret_cast<const float4*>(src + 12);
    s = f0.x*f0.x + f0.y*f0.y + f0.z*f0.z + f0.w*f0.w
      + f1.x*f1.x + f1.y*f1.y + f1.z*f1.z + f1.w*f1.w
      + f2.x*f2.x + f2.y*f2.y + f2.z*f2.z + f2.w*f2.w
      + f3.x*f3.x + f3.y*f3.y + f3.z*f3.z + f3.w*f3.w;
    w = pk16(f0, f1, f2, f3);
  }
#pragma unroll
  for (int m = 32; m >= 1; m >>= 1) s += __shfl_xor(s, m, 64);
  if (lane == 0) x2[row] = s;
  if (lane < 48) {
    unsigned kt = lane >> 2, sl = lane & 3;
    unsigned tile = (unsigned)(row >> 8) * 12 + kt;
    unsigned r8 = row & 255;
    *reinterpret_cast<i32x4v*>(dst + ((size_t)tile << 14) + r8 * 64 + swz4(sl, r8) * 16) = w;
  }
}

// ---------------- fused distance-GEMM (fp8) + per-query top-5 ----------------
// 256 blocks, block b owns mtile b; flat 156 BK64 tiles (13 qb x 12).
// 4-slot LDS ring; 2-tile windows: ONE barrier + one vmcnt(0) per 2 tiles;
// within a window waves drift -> cross-wave LDS/MFMA overlap.
template <int PRE>
__global__ __launch_bounds__(512, 2) void gemm_topk(
    const float* __restrict__ tok, const float* __restrict__ bank,
    const unsigned char* __restrict__ bf8, const unsigned char* __restrict__ tf8,
    const float* __restrict__ y2g, const float* __restrict__ x2g,
    unsigned* __restrict__ cand) {
  __shared__ __align__(16) char sA[4][16384];    // Y ring (bank rows, fp8)
  __shared__ __align__(16) char sB[4][16384];    // X ring (queries, fp8)
  __shared__ float y2s[256];
  __shared__ unsigned fscratch[256 * 5];

  int b = blockIdx.x;          // == mtile
  int tid = threadIdx.x;
  int lane = tid & 63;
  int wid = tid >> 6;
  int wq = wid & 3;            // 64-query strip
  int wm = wid >> 2;           // 128-row m strip
  int l31 = lane & 31;
  int lhi = lane >> 5;

  // per-thread LDS byte offsets within a 16KB slot (2 x b128 per 32B frag)
  int offA[4][2], offB[2][2];
#pragma unroll
  for (int mi = 0; mi < 4; ++mi)
#pragma unroll
    for (int j = 0; j < 2; ++j) {
      int row = wm * 128 + mi * 32 + l31;
      offA[mi][j] = row * 64 + swz4(lhi * 2 + j, row) * 16;
    }
#pragma unroll
  for (int qj = 0; qj < 2; ++qj)
#pragma unroll
    for (int j = 0; j < 2; ++j) {
      int row = wq * 64 + qj * 32 + l31;
      offB[qj][j] = row * 64 + swz4(lhi * 2 + j, row) * 16;
    }

  float thrp[2];
  auto set_thr = [&](int qb) {
#pragma unroll
    for (int qj = 0; qj < 2; ++qj) {
      int qg = qb * 256 + wq * 64 + qj * 32 + l31;
      int qgc = qg < NQ ? qg : NQ - 1;
      float x2q = x2g[qgc];
      thrp[qj] = 768.f - 3.f * sqrtf(1536.f + 4.f * x2q);
    }
  };

  float lv[2][5];
  unsigned li[2][5];
#pragma unroll
  for (int qj = 0; qj < 2; ++qj)
#pragma unroll
    for (int s = 0; s < 5; ++s) { lv[qj][s] = 3.4e38f; li[qj][s] = 0u; }

  f32x16 acc[4][2];
#pragma unroll
  for (int mi = 0; mi < 4; ++mi)
#pragma unroll
    for (int qj = 0; qj < 2; ++qj)
#pragma unroll
      for (int e = 0; e < 16; ++e) acc[mi][qj][e] = 0.f;

  auto insert_pass = [&]() {
#pragma unroll
    for (int mi = 0; mi < 4; ++mi) {
#pragma unroll
      for (int r = 0; r < 16; ++r) {
        int mloc = wm * 128 + mi * 32 + (r & 3) + ((r >> 2) << 3) + (lhi << 2);
        float y2v = y2s[mloc];
#pragma unroll
        for (int qj = 0; qj < 2; ++qj) {
          float d2p = fmaf(-2.f, acc[mi][qj][r], y2v);
          if (d2p < thrp[qj] && d2p < lv[qj][4]) {
            float v = d2p;
            unsigned idv = (unsigned)mloc;
#pragma unroll
            for (int s = 0; s < 5; ++s) {
              bool less = v < lv[qj][s];
              float tv = lv[qj][s]; unsigned ti = li[qj][s];
              if (less) { lv[qj][s] = v; li[qj][s] = idv; v = tv; idv = ti; }
            }
          }
        }
#pragma unroll
        for (int qj = 0; qj < 2; ++qj) acc[mi][qj][r] = 0.f;
      }
    }
  };

  auto flushq = [&](int qb) {
#pragma unroll
    for (int qj = 0; qj < 2; ++qj) {
      float ov[5];
      unsigned oi[5];
#pragma unroll
      for (int j = 0; j < 5; ++j) {
        ov[j] = __shfl_xor(lv[qj][j], 32, 64);
        oi[j] = (unsigned)__shfl_xor((int)li[qj][j], 32, 64);
      }
#pragma unroll
      for (int j = 0; j < 5; ++j) {
        float v = ov[j];
        unsigned idv = oi[j];
#pragma unroll
        for (int s = 0; s < 5; ++s) {
          bool less = v < lv[qj][s];
          float tv = lv[qj][s]; unsigned ti = li[qj][s];
          if (less) { lv[qj][s] = v; li[qj][s] = idv; v = tv; idv = ti; }
        }
      }
    }
    unsigned pk[2][5];
#pragma unroll
    for (int qj = 0; qj < 2; ++qj)
#pragma unroll
      for (int s = 0; s < 5; ++s)
        pk[qj][s] = (lv[qj][s] >= 3.0e38f) ? 0xFFFFFFFFu
                    : ((__float_as_uint(fmaxf(lv[qj][s], 0.f)) & 0xFFFFFF00u) | li[qj][s]);
    if (wm == 1 && lhi == 0) {
#pragma unroll
      for (int qj = 0; qj < 2; ++qj) {
        int ql = wq * 64 + qj * 32 + l31;
#pragma unroll
        for (int s = 0; s < 5; ++s) fscratch[ql * 5 + s] = pk[qj][s];
      }
    }
    __syncthreads();
    if (wm == 0 && lhi == 0) {
#pragma unroll
      for (int qj = 0; qj < 2; ++qj) {
        int ql = wq * 64 + qj * 32 + l31;
#pragma unroll
        for (int j = 0; j < 5; ++j) {
          unsigned v = fscratch[ql * 5 + j];
#pragma unroll
          for (int s = 0; s < 5; ++s) {
            unsigned tv = pk[qj][s];
            bool less = v < tv;
            if (less) { pk[qj][s] = v; v = tv; }
          }
        }
        size_t qg = (size_t)(qb * 256 + ql);
        unsigned* cp = cand + (qg * 256 + b) * 5;
#pragma unroll
        for (int s = 0; s < 5; ++s) cp[s] = pk[qj][s];
      }
    }
#pragma unroll
    for (int qj = 0; qj < 2; ++qj)
#pragma unroll
      for (int s = 0; s < 5; ++s) { lv[qj][s] = 3.4e38f; li[qj][s] = 0u; }
  };

  auto do_mfma = [&](int u) {
    i32x8v aV[4], bV[2];
#pragma unroll
    for (int qj = 0; qj < 2; ++qj) {
      i32x4v lo = *reinterpret_cast<const i32x4v*>(&sB[u][offB[qj][0]]);
      i32x4v hi = *reinterpret_cast<const i32x4v*>(&sB[u][offB[qj][1]]);
      bV[qj] = __builtin_shufflevector(lo, hi, 0, 1, 2, 3, 4, 5, 6, 7);
    }
#pragma unroll
    for (int mi = 0; mi < 4; ++mi) {
      i32x4v lo = *reinterpret_cast<const i32x4v*>(&sA[u][offA[mi][0]]);
      i32x4v hi = *reinterpret_cast<const i32x4v*>(&sA[u][offA[mi][1]]);
      aV[mi] = __builtin_shufflevector(lo, hi, 0, 1, 2, 3, 4, 5, 6, 7);
    }
    __builtin_amdgcn_s_setprio(1);
#pragma unroll
    for (int mi = 0; mi < 4; ++mi) {
      acc[mi][0] = __builtin_amdgcn_mfma_scale_f32_32x32x64_f8f6f4(
          aV[mi], bV[0], acc[mi][0], 0, 0, 0, 0x7F7F7F7F, 0, 0x7F7F7F7F);
      acc[mi][1] = __builtin_amdgcn_mfma_scale_f32_32x32x64_f8f6f4(
          aV[mi], bV[1], acc[mi][1], 0, 0, 0, 0x7F7F7F7F, 0, 0x7F7F7F7F);
    }
    __builtin_amdgcn_s_setprio(0);
  };

  if (tid < 256) y2s[tid] = y2g[b * 256 + tid];
  set_thr(0);

  if constexpr (PRE) {
    auto stageT = [&](int t2, int slot) {
      int kt = t2 % KTILES;
      const char* gA = (const char*)bf8 + ((size_t)(b * KTILES + kt) << 14);
      GLOAD16(gA + (tid << 4), &sA[slot][tid << 4]);
      GLOAD16(gA + 8192 + (tid << 4), &sA[slot][8192 + (tid << 4)]);
      const char* gB = (const char*)tf8 + ((size_t)t2 << 14);
      GLOAD16(gB + (tid << 4), &sB[slot][tid << 4]);
      GLOAD16(gB + 8192 + (tid << 4), &sB[slot][8192 + (tid << 4)]);
    };
    stageT(0, 0);
    stageT(1, 1);
    asm volatile("s_waitcnt vmcnt(0)" ::: "memory");
    __builtin_amdgcn_s_barrier();

    int qbc = 0;
    for (int j = 0; j < TT / 4; ++j) {       // 39 double-windows of 4 tiles
      int t0 = j * 4;
      // ---- window A: compute tiles t0,t0+1 (slots 0,1); stage t0+2,t0+3 (slots 2,3)
      stageT(t0 + 2, 2);
      do_mfma(0);
      stageT(t0 + 3, 3);
      do_mfma(1);
      asm volatile("s_waitcnt vmcnt(0)" ::: "memory");
      __builtin_amdgcn_sched_barrier(0);
      __builtin_amdgcn_s_barrier();
      // ---- window B: compute tiles t0+2,t0+3 (slots 2,3); stage t0+4,t0+5 (slots 0,1)
      {
        int t4 = t0 + 4 < TT ? t0 + 4 : TT - 1;
        int t5 = t0 + 5 < TT ? t0 + 5 : TT - 1;
        stageT(t4, 0);
        do_mfma(2);
        stageT(t5, 1);
        do_mfma(3);
      }
      asm volatile("s_waitcnt vmcnt(0)" ::: "memory");
      __builtin_amdgcn_sched_barrier(0);
      __builtin_amdgcn_s_barrier();
      // ---- qb boundary every 3 double-windows (12 tiles) ----
      if (j % 3 == 2) {
        insert_pass();
        flushq(qbc);
        if (qbc + 1 < NQB) set_thr(qbc + 1);
        ++qbc;
      }
    }
  } else {
    // fallback: VALU-convert fp32->fp8 into slot 0 each tile
    int ktc = 0, qbc = 0;
    for (int t = 0; t < TT; ++t) {
      __syncthreads();
#pragma unroll
      for (int j = 0; j < 2; ++j) {
        int u = tid * 2 + j;
        int row = u >> 2, s = u & 3;
        const float* srcA = bank + (size_t)(b * 256 + row) * CC + ktc * 64 + s * 16;
        float4 f0 = *reinterpret_cast<const float4*>(srcA);
        float4 f1 = *reinterpret_cast<const float4*>(srcA + 4);
        float4 f2 = *reinterpret_cast<const float4*>(srcA + 8);
        float4 f3 = *reinterpret_cast<const float4*>(srcA + 12);
        *reinterpret_cast<i32x4v*>(&sA[0][row * 64 + swz4(s, row) * 16]) = pk16(f0, f1, f2, f3);
        int qr = qbc * 256 + row;
        qr = qr < NQ ? qr : NQ - 1;
        const float* srcB = tok + (size_t)qr * CC + ktc * 64 + s * 16;
        f0 = *reinterpret_cast<const float4*>(srcB);
        f1 = *reinterpret_cast<const float4*>(srcB + 4);
        f2 = *reinterpret_cast<const float4*>(srcB + 8);
        f3 = *reinterpret_cast<const float4*>(srcB + 12);
        *reinterpret_cast<i32x4v*>(&sB[0][row * 64 + swz4(s, row) * 16]) = pk16(f0, f1, f2, f3);
      }
      __syncthreads();
      do_mfma(0);
      if (ktc == KTILES - 1) {
        __syncthreads();
        insert_pass();
        flushq(qbc);
        if (qbc + 1 < NQB) set_thr(qbc + 1);
        ktc = 0; ++qbc;
      } else {
        ++ktc;
      }
    }
  }
}

// ---------------- merge candidates, exact fp32 rescoring (top-16), final score ----
__global__ __launch_bounds__(256) void merge_rescore(
    const float* __restrict__ tok, const float* __restrict__ bank,
    const unsigned* __restrict__ cand, float* __restrict__ out) {
  int q = blockIdx.x * 4 + (threadIdx.x >> 6);
  int lane = threadIdx.x & 63;
  const unsigned* cp = cand + (size_t)q * 1280;
  unsigned e[20];   // 4 blocks x 5 entries per lane
#pragma unroll
  for (int j = 0; j < 20; ++j) e[j] = cp[lane * 20 + j];
  unsigned gids[16];
#pragma unroll
  for (int r = 0; r < 16; ++r) {
    unsigned bv = e[0];
#pragma unroll
    for (int j = 1; j < 20; ++j) bv = e[j] < bv ? e[j] : bv;
    unsigned rv = bv;
    int rl = lane;
#pragma unroll
    for (int m = 32; m >= 1; m >>= 1) {
      unsigned ov = (unsigned)__shfl_xor((int)rv, m, 64);
      int ol = __shfl_xor(rl, m, 64);
      if (ov < rv || (ov == rv && ol < rl)) { rv = ov; rl = ol; }
    }
    unsigned gid = 0;
    if (lane == rl) {
      bool done = false;
#pragma unroll
      for (int j = 0; j < 20; ++j) {
        if (!done && e[j] == rv) {
          gid = (unsigned)((lane * 4 + j / 5) * 256) + (e[j] & 255u);
          e[j] = 0xFFFFFFFFu;
          done = true;
        }
      }
    }
    gids[r] = (unsigned)__shfl((int)gid, rl, 64);
  }
  float xv[12];
  {
    const float* xp = tok + (size_t)q * CC + lane * 12;
    float4 a = *reinterpret_cast<const float4*>(xp);
    float4 bq = *reinterpret_cast<const float4*>(xp + 4);
    float4 cc4 = *reinterpret_cast<const float4*>(xp + 8);
    xv[0] = a.x; xv[1] = a.y; xv[2] = a.z; xv[3] = a.w;
    xv[4] = bq.x; xv[5] = bq.y; xv[6] = bq.z; xv[7] = bq.w;
    xv[8] = cc4.x; xv[9] = cc4.y; xv[10] = cc4.z; xv[11] = cc4.w;
  }
  float d2e[16];
#pragma unroll
  for (int r = 0; r < 16; ++r) {
    const float* yp = bank + (size_t)(gids[r] & (MM - 1)) * CC + lane * 12;
    float4 a = *reinterpret_cast<const float4*>(yp);
    float4 bq = *reinterpret_cast<const float4*>(yp + 4);
    float4 cc4 = *reinterpret_cast<const float4*>(yp + 8);
    float yv[12];
    yv[0] = a.x; yv[1] = a.y; yv[2] = a.z; yv[3] = a.w;
    yv[4] = bq.x; yv[5] = bq.y; yv[6] = bq.z; yv[7] = bq.w;
    yv[8] = cc4.x; yv[9] = cc4.y; yv[10] = cc4.z; yv[11] = cc4.w;
    float s = 0.f;
#pragma unroll
    for (int e2 = 0; e2 < 12; ++e2) {
      float d = xv[e2] - yv[e2];
      s = fmaf(d, d, s);
    }
#pragma unroll
    for (int m = 32; m >= 1; m >>= 1) s += __shfl_xor(s, m, 64);
    d2e[r] = s;
  }
  float d1sq = 0.f, d5sq = 0.f;
#pragma unroll
  for (int r5 = 0; r5 < 5; ++r5) {
    float bv = d2e[0];
    int bj = 0;
#pragma unroll
    for (int j = 1; j < 16; ++j)
      if (d2e[j] < bv) { bv = d2e[j]; bj = j; }
    if (r5 == 0) d1sq = bv;
    if (r5 == 4) d5sq = bv;
#pragma unroll
    for (int j = 0; j < 16; ++j)
      if (j == bj) d2e[j] = 3.4e38f;
  }
  float d1 = sqrtf(fmaxf(d1sq, 0.f));
  float d5 = sqrtf(fmaxf(d5sq, 0.f));
  float gap = fmaxf(d5 - d1, 0.f);
  float sc = d1 * (1.f - expf(-gap));
  if (lane == 0) out[q] = sc;
}

extern "C" void kernel_launch(void* const* d_in, const int* in_sizes, int n_in,
                              void* d_out, int out_size, void* d_ws, size_t ws_size,
                              hipStream_t stream) {
  const float* tok = (const float*)d_in[0];   // 3136x768 fp32
  const float* bank = (const float*)d_in[1];  // 65536x768 fp32
  float* out = (float*)d_out;                 // 3136 fp32
  char* ws = (char*)d_ws;
  float* y2 = (float*)ws;                                     // 256KB
  float* x2 = (float*)(ws + 262144);                          // 13KB
  unsigned* cand = (unsigned*)(ws + 1048576);                 // 17.04MB
  unsigned char* bf8 = (unsigned char*)(ws + 18874368);       // 50.33MB (fp8 bank tiles)
  unsigned char* tf8 = (unsigned char*)(ws + 69206016);       // 2.56MB (fp8 tok tiles)
  const size_t WS_NEED = 71761920ull;

  if (ws_size >= WS_NEED) {
    convert_bank_y2<<<MM / 4, 256, 0, stream>>>(bank, bf8, y2);
    convert_tok_x2<<<QPAD / 4, 256, 0, stream>>>(tok, tf8, x2);
    gemm_topk<1><<<256, 512, 0, stream>>>(tok, bank, bf8, tf8, y2, x2, cand);
  } else {
    prep_sumsq<<<(MM + QPAD) / 4, 256, 0, stream>>>(tok, bank, y2, x2);
    gemm_topk<0><<<256, 512, 0, stream>>>(tok, bank, bf8, tf8, y2, x2, cand);
  }
  merge_rescore<<<NQ / 4, 256, 0, stream>>>(tok, bank, cand, out);
}